// Round 14
// baseline (1655.039 us; speedup 1.0000x reference)
//
#include <hip/hip_runtime.h>
#include <hip/hip_bf16.h>
#include <hip/hip_cooperative_groups.h>

namespace cg = cooperative_groups;

// ---------------------------------------------------------------------------
// LinearSystem: chunked parallel scan (128 chunks x 8 steps), bf16 MFMA.
// Round 14 = R8 (best, 703us) with the 15-dispatch phase1+init+KS chain
// replaced by ONE cooperative kernel (chain_k) using grid.sync() between
// stages. Per-tile GEMM identical to R8's gemm_k. Drive computes F^2 aux.
// p3obs_k is the R8 single-buffered version verbatim.
// ---------------------------------------------------------------------------

typedef short bfrag __attribute__((ext_vector_type(8)));   // 8 x bf16 bits
typedef float f32x4 __attribute__((ext_vector_type(4)));

__device__ __host__ inline unsigned short f2bf(float f) {
    union { float f; unsigned u; } x; x.f = f;
    unsigned r = x.u + 0x7fffu + ((x.u >> 16) & 1u);   // RNE
    return (unsigned short)(r >> 16);
}
__device__ inline float bf2f(unsigned short h) {
    union { unsigned u; float f; } x; x.u = ((unsigned)h) << 16;
    return x.f;
}

#define MSL 262144L   // 512*512 matrix stride

// ======================= standalone GEMM (drive only) ======================
struct GemmDesc {
    const unsigned short* a0; const unsigned short* a1;  // A (k < ksplit -> a0)
    const unsigned short* b;                 // B, bf16, (N,K) row-major (B^T)
    float* c;                                // f32 C out (nullable)
    const unsigned short* cmbeta;            // bf16 beta source (beta==2)
    unsigned short* cm;                      // bf16 mirror out (nullable)
    unsigned short* cmT;                     // bf16 transposed mirror (512x512)
    long a0_base, a0_os, a0_is;
    long a1_base, a1_os, a1_is;
    long a_zq, a_zr;
    long b_base, b_ldb, b_zq, b_zr;
    long c_base, c_os, c_is, c_zq, c_zr;
    long cm_base, cmb_base, cmT_base;
    long a_shift;
    int a0_icl, a1_icl, c_icl, zdivl;
    int ksplit, K, beta;
    int gxl, gyl, gz_main;
    const unsigned short* xa; const unsigned short* xb;
    unsigned short* xcm; unsigned short* xcmT;
};

__global__ __launch_bounds__(256) void gemm_k(GemmDesc d) {
    __shared__ __align__(16) unsigned short As[2][128 * 64];
    __shared__ __align__(16) unsigned short Bs[2][128 * 64];
    const int tid  = threadIdx.x;
    const int lane = tid & 63;
    const int w    = tid >> 6;
    const int wrow = (w >> 1) * 64, wcol = (w & 1) * 64;

    const unsigned nx = gridDim.x, ny = gridDim.y;
    const unsigned nwg = nx * ny * gridDim.z;
    unsigned wid = blockIdx.x + nx * (blockIdx.y + ny * blockIdx.z);
    if ((nwg & 7) == 0) wid = (wid & 7) * (nwg >> 3) + (wid >> 3);
    const int bx = wid & (nx - 1);
    const int by = (wid >> d.gxl) & (ny - 1);
    int bz = wid >> (d.gxl + d.gyl);

    if (bz >= d.gz_main) {                   // aux: 512x512 power-chain GEMM
        if (by >= 4) return;
        const long za = (long)(bz - d.gz_main) * MSL;
        d.a0 = d.xa; d.a0_base = za; d.a0_os = 512; d.a0_is = 0; d.a0_icl = 0;
        d.a1 = nullptr;
        d.b = d.xb; d.b_base = 0; d.b_ldb = 512; d.b_zq = d.b_zr = 0;
        d.K = 512; d.ksplit = 1 << 30; d.beta = 0; d.a_shift = 0;
        d.a_zq = d.a_zr = 0;
        d.c = nullptr; d.cm = d.xcm; d.cm_base = za;
        d.c_os = 512; d.c_is = 0; d.c_icl = 0; d.c_zq = d.c_zr = 0; d.c_base = 0;
        d.cmT = d.xcmT; d.cmT_base = za;
        bz = 0;
    }
    const long zq = (long)bz >> d.zdivl;
    const long zr = (long)bz & ((1L << d.zdivl) - 1);
    const int row0 = by * 128;
    const int col0 = bx * 128;

    const int g_r = tid >> 3;
    const int g_k = (tid & 7) * 8;
    const int swz = (g_r & 7) << 3;
    const long za_ = zq * d.a_zq + zr * d.a_zr;
    const long zb_ = zq * d.b_zq + zr * d.b_zr;

    const long m0a = (1L << d.a0_icl) - 1, m1a = (1L << d.a1_icl) - 1;
    long a0off[4], a1off[4], boff[4];
#pragma unroll
    for (int i = 0; i < 4; ++i) {
        long ar = (long)row0 + i * 32 + g_r - d.a_shift;
        if (ar < 0) ar = 0;
        a0off[i] = d.a0_base + za_ + (ar >> d.a0_icl) * d.a0_os + (ar & m0a) * d.a0_is;
        a1off[i] = d.a1 ? (d.a1_base + za_ + (ar >> d.a1_icl) * d.a1_os + (ar & m1a) * d.a1_is) : 0;
        boff[i]  = d.b_base + zb_ + (long)(col0 + i * 32 + g_r) * d.b_ldb;
    }

    bfrag ar_[4], br_[4];
    auto LOADT = [&](int t) {
        const int k0 = t * 64;
        const bool s1 = (k0 >= d.ksplit);
        const int kb = (s1 ? k0 - d.ksplit : k0) + g_k;
        const unsigned short* sp = s1 ? d.a1 : d.a0;
#pragma unroll
        for (int i = 0; i < 4; ++i)
            ar_[i] = *(const bfrag*)(sp + (s1 ? a1off[i] : a0off[i]) + kb);
#pragma unroll
        for (int i = 0; i < 4; ++i) br_[i] = *(const bfrag*)(d.b + boff[i] + k0 + g_k);
    };
    auto WRT = [&](int buf) {
#pragma unroll
        for (int i = 0; i < 4; ++i) {
            *(bfrag*)&As[buf][(i * 32 + g_r) * 64 + (g_k ^ swz)] = ar_[i];
            *(bfrag*)&Bs[buf][(i * 32 + g_r) * 64 + (g_k ^ swz)] = br_[i];
        }
    };

    f32x4 acc[4][4] = {};
    const int nt = d.K / 64;

    LOADT(0); WRT(0); __syncthreads();
    int cur = 0;
    for (int t = 0; t < nt; ++t) {
        if (t + 1 < nt) LOADT(t + 1);
#pragma unroll
        for (int ks = 0; ks < 2; ++ks) {
            const int kk = ks * 32 + (lane >> 4) * 8;
            bfrag af[4], bf_[4];
#pragma unroll
            for (int mt = 0; mt < 4; ++mt) {
                const int r = wrow + mt * 16 + (lane & 15);
                af[mt] = *(const bfrag*)&As[cur][r * 64 + (kk ^ ((r & 7) << 3))];
            }
#pragma unroll
            for (int nn = 0; nn < 4; ++nn) {
                const int r = wcol + nn * 16 + (lane & 15);
                bf_[nn] = *(const bfrag*)&Bs[cur][r * 64 + (kk ^ ((r & 7) << 3))];
            }
#pragma unroll
            for (int mt = 0; mt < 4; ++mt)
#pragma unroll
                for (int nn = 0; nn < 4; ++nn)
                    acc[mt][nn] = __builtin_amdgcn_mfma_f32_16x16x32_bf16(
                        af[mt], bf_[nn], acc[mt][nn], 0, 0, 0);
        }
        if (t + 1 < nt) WRT(cur ^ 1);
        __syncthreads();
        cur ^= 1;
    }

    const long zc = zq * d.c_zq + zr * d.c_zr;
    const long mc = (1L << d.c_icl) - 1;
#pragma unroll
    for (int mt = 0; mt < 4; ++mt) {
        const int rb = row0 + wrow + mt * 16 + ((lane >> 4) << 2);
#pragma unroll
        for (int nn = 0; nn < 4; ++nn) {
            const int cc = col0 + wcol + nn * 16 + (lane & 15);
#pragma unroll
            for (int j = 0; j < 4; ++j) {
                const long r = rb + j;
                const long off = zc + (r >> d.c_icl) * d.c_os + (r & mc) * d.c_is + cc;
                float v = (r < d.a_shift) ? 0.0f : acc[mt][nn][j];
                if (d.beta == 2) v += bf2f(d.cmbeta[d.cmb_base + off]);
                if (d.c)  d.c[d.c_base + off] = v;
                if (d.cm) d.cm[d.cm_base + off] = f2bf(v);
                if (d.cmT) d.cmT[d.cmT_base + zc + (long)cc * 512 + r] = f2bf(v);
            }
        }
    }
}

// ======================= cooperative chain =================================
struct TileDesc {
    const unsigned short* a0;
    const unsigned short* b;
    const unsigned short* cmbeta;
    unsigned short* cm;
    unsigned short* cmT;
    long a0_base, a0_os, a0_is;
    long b_base;
    long c_base, c_os, c_is;
    long a_shift;
    int a0_icl, c_icl, beta;
};

// R8's 128x128 K=512 tile as a device function (LDS declared inside).
__device__ __noinline__ void gemm_tile(const TileDesc d, int bx, int by) {
    __shared__ __align__(16) unsigned short As[2][128 * 64];
    __shared__ __align__(16) unsigned short Bs[2][128 * 64];
    const int tid  = threadIdx.x;
    const int lane = tid & 63;
    const int w    = tid >> 6;
    const int wrow = (w >> 1) * 64, wcol = (w & 1) * 64;
    const int row0 = by * 128, col0 = bx * 128;
    const int g_r = tid >> 3;
    const int g_k = (tid & 7) * 8;
    const int swz = (g_r & 7) << 3;

    const long m0a = (1L << d.a0_icl) - 1;
    long a0off[4], boff[4];
#pragma unroll
    for (int i = 0; i < 4; ++i) {
        long ar = (long)row0 + i * 32 + g_r - d.a_shift;
        if (ar < 0) ar = 0;
        a0off[i] = d.a0_base + (ar >> d.a0_icl) * d.a0_os + (ar & m0a) * d.a0_is;
        boff[i]  = d.b_base + (long)(col0 + i * 32 + g_r) * 512;
    }

    bfrag ar_[4], br_[4];
    auto LOADT = [&](int t) {
        const int kb = t * 64 + g_k;
#pragma unroll
        for (int i = 0; i < 4; ++i) ar_[i] = *(const bfrag*)(d.a0 + a0off[i] + kb);
#pragma unroll
        for (int i = 0; i < 4; ++i) br_[i] = *(const bfrag*)(d.b + boff[i] + kb);
    };
    auto WRT = [&](int buf) {
#pragma unroll
        for (int i = 0; i < 4; ++i) {
            *(bfrag*)&As[buf][(i * 32 + g_r) * 64 + (g_k ^ swz)] = ar_[i];
            *(bfrag*)&Bs[buf][(i * 32 + g_r) * 64 + (g_k ^ swz)] = br_[i];
        }
    };

    f32x4 acc[4][4] = {};
    LOADT(0); WRT(0); __syncthreads();
    int cur = 0;
    for (int t = 0; t < 8; ++t) {
        if (t < 7) LOADT(t + 1);
#pragma unroll
        for (int ks = 0; ks < 2; ++ks) {
            const int kk = ks * 32 + (lane >> 4) * 8;
            bfrag af[4], bf_[4];
#pragma unroll
            for (int mt = 0; mt < 4; ++mt) {
                const int r = wrow + mt * 16 + (lane & 15);
                af[mt] = *(const bfrag*)&As[cur][r * 64 + (kk ^ ((r & 7) << 3))];
            }
#pragma unroll
            for (int nn = 0; nn < 4; ++nn) {
                const int r = wcol + nn * 16 + (lane & 15);
                bf_[nn] = *(const bfrag*)&Bs[cur][r * 64 + (kk ^ ((r & 7) << 3))];
            }
#pragma unroll
            for (int mt = 0; mt < 4; ++mt)
#pragma unroll
                for (int nn = 0; nn < 4; ++nn)
                    acc[mt][nn] = __builtin_amdgcn_mfma_f32_16x16x32_bf16(
                        af[mt], bf_[nn], acc[mt][nn], 0, 0, 0);
        }
        if (t < 7) WRT(cur ^ 1);
        __syncthreads();
        cur ^= 1;
    }

    const long mc = (1L << d.c_icl) - 1;
#pragma unroll
    for (int mt = 0; mt < 4; ++mt) {
        const int rb = row0 + wrow + mt * 16 + ((lane >> 4) << 2);
#pragma unroll
        for (int nn = 0; nn < 4; ++nn) {
            const int cc = col0 + wcol + nn * 16 + (lane & 15);
#pragma unroll
            for (int j = 0; j < 4; ++j) {
                const long r = rb + j;
                const long off = d.c_base + (r >> d.c_icl) * d.c_os + (r & mc) * d.c_is + cc;
                float v = (r < d.a_shift) ? 0.0f : acc[mt][nn][j];
                if (d.beta == 2) v += bf2f(d.cmbeta[off]);
                d.cm[off] = f2bf(v);
                if (d.cmT) d.cmT[(long)cc * 512 + r] = f2bf(v);
            }
        }
    }
}

struct ChainArgs {
    unsigned short *Smir, *G, *Gt, *Qb, *Qtb, *a0m, *a1m;
    const float* st0;
};

// phase1 (7 steps) + init_carry + Kogge-Stone (7 rounds), one launch.
__global__ __launch_bounds__(256) void chain_k(ChainArgs a) {
    cg::grid_group grid = cg::this_grid();
    const long MS = MSL;
    const long TOS = 524288, COS = 4096;

    // ---- phase 1: Smir[t] += Smir[t-1] @ F^T, t = 1..7 ----
    for (int k = 1; k < 8; ++k) {
        TileDesc d = {};
        d.a0 = a.Smir; d.a0_base = (long)(k - 1) * 512;
        d.a0_icl = 7; d.a0_os = TOS; d.a0_is = COS;
        d.b = a.G;
        d.cmbeta = a.Smir; d.cm = a.Smir;
        d.c_base = (long)k * 512; d.c_icl = 7; d.c_os = TOS; d.c_is = COS;
        d.beta = 2;
        // aux schedule: k=1 -> G[2..3]=F^3,F^4 ; k=2 -> G[4..7]=F^5..F^8 ;
        //               k=3..7 -> Qb[0..4]=F^16..F^256 (+T)
        const unsigned short *xa, *xb; unsigned short *xcm, *xcmT; int n;
        if (k == 1)      { xa = a.G;  xb = a.Gt + MS;     xcm = a.G + 2 * MS;  xcmT = a.Gt + 2 * MS; n = 2; }
        else if (k == 2) { xa = a.G;  xb = a.Gt + 3 * MS; xcm = a.G + 4 * MS;  xcmT = a.Gt + 4 * MS; n = 4; }
        else { const int j = k - 3;
            xa = (j == 0) ? (a.G + 7 * MS) : (a.Qb + (long)(j - 1) * MS);
            xb = (j == 0) ? (a.Gt + 7 * MS) : (a.Qtb + (long)(j - 1) * MS);
            xcm = a.Qb + (long)j * MS; xcmT = a.Qtb + (long)j * MS; n = 1; }
        const int ntiles = 256 + 16 * n;
        for (int t = blockIdx.x; t < ntiles; t += gridDim.x) {
            if (t < 256) gemm_tile(d, t & 3, t >> 2);
            else {
                const int q = t - 256;
                const long za = (long)(q >> 4) * MS;
                TileDesc e = {};
                e.a0 = xa; e.a0_base = za; e.a0_icl = 0; e.a0_os = 512;
                e.b = xb;
                e.cm = xcm + za; e.cmT = xcmT + za;
                e.c_icl = 0; e.c_os = 512;
                gemm_tile(e, q & 3, (q >> 2) & 3);
            }
        }
        __threadfence();
        grid.sync();
    }

    // ---- initial carries a[c]: c==0 from st0 (f32), else Smir[c-1, t=7] ----
    for (long i = (long)blockIdx.x * 256 + threadIdx.x; i < 524288; i += 65536) {
        const long i8 = i * 8;
        const long c = i8 >> 15, rem = i8 & 32767L;
        const long b = rem >> 9, s = rem & 511L;
        union { bfrag v; unsigned short h[8]; } t;
        if (c == 0) {
            const float* p = a.st0 + b * 512 + s;
            f32x4 x0 = *(const f32x4*)p, x1 = *(const f32x4*)(p + 4);
#pragma unroll
            for (int q = 0; q < 4; ++q) { t.h[q] = f2bf(x0[q]); t.h[4 + q] = f2bf(x1[q]); }
        } else {
            t.v = *(const bfrag*)(a.Smir + b * 524288L + (c - 1) * 4096L + 3584L + s);
        }
        *(bfrag*)(a.a0m + i8) = t.v;
    }
    __threadfence();
    grid.sync();

    // ---- Kogge-Stone: nxt[r] = cur[r] + (r>=s*64 ? cur[r-s*64]@(F^{8s})^T : 0)
    //      aux at s==1: Qb[5]=F^512 = Qb[4]^2
    unsigned short* curm = a.a0m;
    unsigned short* nxtm = a.a1m;
    for (int s = 1; s < 128; s <<= 1) {
        TileDesc d = {};
        d.a0 = curm; d.a0_icl = 0; d.a0_os = 512;
        d.b = (s == 1) ? (a.G + 7 * MS) : (a.Qb + (long)(__builtin_ctz(s) - 1) * MS);
        d.cmbeta = curm; d.cm = nxtm;
        d.c_icl = 0; d.c_os = 512;
        d.beta = 2; d.a_shift = (long)s * 64;
        const int ntiles = 256 + ((s == 1) ? 16 : 0);
        for (int t = blockIdx.x; t < ntiles; t += gridDim.x) {
            if (t < 256) gemm_tile(d, t & 3, t >> 2);
            else {
                const int q = t - 256;
                TileDesc e = {};
                e.a0 = a.Qb + 4 * MS; e.a0_icl = 0; e.a0_os = 512;
                e.b = a.Qtb + 4 * MS;
                e.cm = a.Qb + 5 * MS;
                e.c_icl = 0; e.c_os = 512;
                gemm_tile(e, q & 3, (q >> 2) & 3);
            }
        }
        __threadfence();
        grid.sync();
        unsigned short* tm = curm; curm = nxtm; nxtm = tm;
    }
}

// ======================= fused phase3 + obs (R8 version) ===================
__global__ __launch_bounds__(512) void p3obs_k(
        const unsigned short* __restrict__ carry, const unsigned short* __restrict__ Gm,
        const unsigned short* __restrict__ Smir, const unsigned short* __restrict__ BopO,
        const float* __restrict__ Vn, float* __restrict__ states, float* __restrict__ obs) {
    __shared__ __align__(16) unsigned char lds[163840];
    unsigned short* As1 = (unsigned short*)(lds);            // [128][64]  (phase A)
    unsigned short* Bs1 = (unsigned short*)(lds + 16384);    // [512][64]  (phase A)
    unsigned short* Sb  = (unsigned short*)(lds);            // [128][512] (phase B)
    unsigned short* A2  = (unsigned short*)(lds);            // [128][64]  (B2, over Sb)
    unsigned short* Ts  = (unsigned short*)(lds + 131072);   // [256][64]  (phase B)

    const int tid  = threadIdx.x;
    const int lane = tid & 63;
    const int w    = tid >> 6;               // 0..7
    const int wm   = w >> 2, wn = w & 3;     // 2 x 4 wave grid
    const int by   = blockIdx.y;             // 0..63
    const int k    = blockIdx.z;             // 0..7
    const unsigned short* G = Gm + (long)k * MSL;   // F^{k+1}

    f32x4 acc[4][8] = {};

    // ---------- GEMM1 ----------
    for (int kt = 0; kt < 8; ++kt) {
        __syncthreads();
#pragma unroll
        for (int i = 0; i < 2; ++i) {        // A tile: carry rows
            const int fi = tid + i * 512;
            const int row = fi >> 3, kk = (fi & 7) * 8;
            const long rg = (long)by * 128 + row;
            const long c = rg >> 6, b = rg & 63;
            bfrag v = *(const bfrag*)(carry + c * 32768 + b * 512 + kt * 64 + kk);
            *(bfrag*)&As1[row * 64 + (kk ^ ((row & 7) << 3))] = v;
        }
#pragma unroll
        for (int i = 0; i < 8; ++i) {        // B tile: G rows (all 512)
            const int fi = tid + i * 512;
            const int row = fi >> 3, kk = (fi & 7) * 8;
            bfrag v = *(const bfrag*)(G + (long)row * 512 + kt * 64 + kk);
            *(bfrag*)&Bs1[row * 64 + (kk ^ ((row & 7) << 3))] = v;
        }
        __syncthreads();
#pragma unroll
        for (int ks = 0; ks < 2; ++ks) {
            const int kk = ks * 32 + (lane >> 4) * 8;
            bfrag af[4], bf_[8];
#pragma unroll
            for (int mt = 0; mt < 4; ++mt) {
                const int r = wm * 64 + mt * 16 + (lane & 15);
                af[mt] = *(const bfrag*)&As1[r * 64 + (kk ^ ((r & 7) << 3))];
            }
#pragma unroll
            for (int nt = 0; nt < 8; ++nt) {
                const int n = wn * 128 + nt * 16 + (lane & 15);
                bf_[nt] = *(const bfrag*)&Bs1[n * 64 + (kk ^ ((n & 7) << 3))];
            }
#pragma unroll
            for (int mt = 0; mt < 4; ++mt)
#pragma unroll
                for (int nt = 0; nt < 8; ++nt)
                    acc[mt][nt] = __builtin_amdgcn_mfma_f32_16x16x32_bf16(
                        af[mt], bf_[nt], acc[mt][nt], 0, 0, 0);
        }
    }
    __syncthreads();

    // ---------- epilogue 1: +local, write states, build Sb ----------
#pragma unroll
    for (int mt = 0; mt < 4; ++mt) {
#pragma unroll
        for (int nt = 0; nt < 8; ++nt) {
#pragma unroll
            for (int j = 0; j < 4; ++j) {
                const int lr = wm * 64 + mt * 16 + ((lane >> 4) << 2) + j;
                const int cc = wn * 128 + nt * 16 + (lane & 15);
                const long rg = (long)by * 128 + lr;
                const long c = rg >> 6, b = rg & 63;
                const long t = c * 8 + k;
                float v = acc[mt][nt][j] + bf2f(Smir[b * 524288L + t * 512 + cc]);
                states[b * 524288L + t * 512 + cc] = v;
                Sb[lr * 512 + (cc ^ ((lr & 7) << 3))] = f2bf(v);
            }
        }
    }

    // ---------- GEMM2: obs = [Sb | cvt(Vn)] @ BopO^T ----------
    f32x4 acc2[4][4] = {};
    for (int kt = 0; kt < 12; ++kt) {
        __syncthreads();
#pragma unroll
        for (int i = 0; i < 4; ++i) {        // Ts: BopO rows 0..255
            const int fi = tid + i * 512;
            const int row = fi >> 3, kk = (fi & 7) * 8;
            bfrag v = *(const bfrag*)(BopO + (long)row * 768 + kt * 64 + kk);
            *(bfrag*)&Ts[row * 64 + (kk ^ ((row & 7) << 3))] = v;
        }
        if (kt >= 8) {
#pragma unroll
            for (int i = 0; i < 2; ++i) {    // A2: Vn f32 -> bf16
                const int fi = tid + i * 512;
                const int row = fi >> 3, kk = (fi & 7) * 8;
                const long rg = (long)by * 128 + row;
                const long c = rg >> 6, b = rg & 63;
                const long t = c * 8 + k;
                const float* p = Vn + b * 262144L + t * 256 + (kt - 8) * 64 + kk;
                f32x4 x0 = *(const f32x4*)p, x1 = *(const f32x4*)(p + 4);
                union { bfrag v; unsigned short h[8]; } u;
#pragma unroll
                for (int q = 0; q < 4; ++q) { u.h[q] = f2bf(x0[q]); u.h[4 + q] = f2bf(x1[q]); }
                *(bfrag*)&A2[row * 64 + (kk ^ ((row & 7) << 3))] = u.v;
            }
        }
        __syncthreads();
#pragma unroll
        for (int ks = 0; ks < 2; ++ks) {
            const int kk = ks * 32 + (lane >> 4) * 8;
            bfrag af[4], bf_[4];
#pragma unroll
            for (int mt = 0; mt < 4; ++mt) {
                const int r = wm * 64 + mt * 16 + (lane & 15);
                af[mt] = (kt < 8)
                    ? *(const bfrag*)&Sb[r * 512 + ((kt * 64 + kk) ^ ((r & 7) << 3))]
                    : *(const bfrag*)&A2[r * 64 + (kk ^ ((r & 7) << 3))];
            }
#pragma unroll
            for (int nt = 0; nt < 4; ++nt) {
                const int n = wn * 64 + nt * 16 + (lane & 15);
                bf_[nt] = *(const bfrag*)&Ts[n * 64 + (kk ^ ((n & 7) << 3))];
            }
#pragma unroll
            for (int mt = 0; mt < 4; ++mt)
#pragma unroll
                for (int nt = 0; nt < 4; ++nt)
                    acc2[mt][nt] = __builtin_amdgcn_mfma_f32_16x16x32_bf16(
                        af[mt], bf_[nt], acc2[mt][nt], 0, 0, 0);
        }
    }
    // ---------- epilogue 2: write obs ----------
#pragma unroll
    for (int mt = 0; mt < 4; ++mt) {
#pragma unroll
        for (int nt = 0; nt < 4; ++nt) {
#pragma unroll
            for (int j = 0; j < 4; ++j) {
                const int lr = wm * 64 + mt * 16 + ((lane >> 4) << 2) + j;
                const int cc = wn * 64 + nt * 16 + (lane & 15);
                const long rg = (long)by * 128 + lr;
                const long c = rg >> 6, b = rg & 63;
                const long t = c * 8 + k;
                obs[b * 262144L + t * 256 + cc] = acc2[mt][nt][j];
            }
        }
    }
}

// f32 -> bf16 bulk conversion, 8 elems/thread.
__global__ void cvt_k(const float* src, unsigned short* dst, long n) {
    long i = ((long)blockIdx.x * 256 + threadIdx.x) * 8;
    const long stride = (long)gridDim.x * 256 * 8;
    for (; i < n; i += stride) {
        f32x4 x0 = *(const f32x4*)(src + i), x1 = *(const f32x4*)(src + i + 4);
        union { bfrag v; unsigned short h[8]; } t;
#pragma unroll
        for (int q = 0; q < 4; ++q) { t.h[q] = f2bf(x0[q]); t.h[4 + q] = f2bf(x1[q]); }
        *(bfrag*)(dst + i) = t.v;
    }
}

// Build bf16 operators: BopD (512x768)=[B_mat|sqrt_S_W], BopO (256x768)=[H|sqrt_S_V],
// G[0]=F, Gt[0]=F^T.
__global__ void build_ops_k(const float* F, const float* Bm, const float* H,
                            const float* sW, const float* sV,
                            unsigned short* bopd, unsigned short* bopo,
                            unsigned short* G1, unsigned short* Gt1) {
    int i = blockIdx.x * 256 + threadIdx.x;
    const int n1 = 512 * 768, n2 = 256 * 768, n3 = 512 * 512;
    if (i < n1) { int n = i / 768, k = i % 768;
        bopd[i] = f2bf(k < 256 ? Bm[n * 256 + k] : sW[n * 512 + (k - 256)]); return; }
    i -= n1;
    if (i < n2) { int o = i / 768, k = i % 768;
        bopo[i] = f2bf(k < 512 ? H[o * 512 + k] : sV[o * 256 + (k - 512)]); return; }
    i -= n2;
    if (i < n3) { G1[i] = f2bf(F[i]); return; }
    i -= n3;
    if (i < n3) { int r = i / 512, c = i % 512; Gt1[i] = f2bf(F[c * 512 + r]); }
}

static GemmDesc D0() {
    GemmDesc d = {};
    d.zdivl = 30;
    d.ksplit = 1 << 30;
    d.b_ldb = 512; d.K = 512;
    d.gz_main = 1 << 30;
    return d;
}

extern "C" void kernel_launch(void* const* d_in, const int* in_sizes, int n_in,
                              void* d_out, int out_size, void* d_ws, size_t ws_size,
                              hipStream_t stream) {
    const float* st0 = (const float*)d_in[0];
    const float* inp = (const float*)d_in[1];
    const float* Wn  = (const float*)d_in[2];
    const float* Vn  = (const float*)d_in[3];
    const float* F   = (const float*)d_in[4];
    const float* Bm  = (const float*)d_in[5];
    const float* H   = (const float*)d_in[6];
    const float* sW  = (const float*)d_in[7];
    const float* sV  = (const float*)d_in[8];

    float* states = (float*)d_out;              // (64,1024,512) f32
    float* obs    = states + 33554432L;         // (64,1024,256) f32

    const long MS = MSL;
    const long CB = 32768;
    const int  NC = 128;

    // d_out states region: inp/Wn bf16 scratch (dead after drive).
    unsigned short* inpb = (unsigned short*)states;
    unsigned short* Wnb  = inpb + 16777216L;

    // ws layout (all bf16 bits) — identical to R8
    unsigned short* Smir = (unsigned short*)d_ws;          // 33,554,432
    unsigned short* G    = Smir + 33554432L;               // G[j]=F^{j+1}, j=0..7
    unsigned short* Gt   = G + 8 * MS;
    unsigned short* Qb   = Gt + 8 * MS;                    // F^{16*2^j}, j=0..5
    unsigned short* Qtb  = Qb + 6 * MS;                    // j=0..4 (+1 spare)
    unsigned short* BopD = Qtb + 6 * MS;                   // 512*768
    unsigned short* BopO = BopD + 512 * 768;               // 256*768
    unsigned short* a0m  = BopO + 256 * 768;               // NC*CB carries
    unsigned short* a1m  = a0m + (long)NC * CB;
    (void)in_sizes; (void)n_in; (void)out_size; (void)ws_size;

    auto L = [&](const GemmDesc& d, int gx, int gxl, int gy, int gyl, int gz) {
        GemmDesc dd = d; dd.gxl = gxl; dd.gyl = gyl;
        gemm_k<<<dim3(gx, gy, gz), dim3(256), 0, stream>>>(dd);
    };

    // 0) bf16 prepass: inp, Wn -> d_out scratch
    cvt_k<<<dim3(2048), dim3(256), 0, stream>>>(inp, inpb, 16777216L);
    cvt_k<<<dim3(2048), dim3(256), 0, stream>>>(Wn, Wnb, 33554432L);

    // 1) operators + F, F^T
    build_ops_k<<<dim3(4352), dim3(256), 0, stream>>>(F, Bm, H, sW, sV, BopD, BopO, G, Gt);

    // 2) drive = [inputs | W_noise] @ BopD^T -> Smir ; aux: F^2 (+T)
    {
        GemmDesc d = D0();
        d.a0 = inpb; d.a0_os = 256;
        d.a1 = Wnb;  d.a1_os = 512;
        d.ksplit = 256; d.K = 768;
        d.b = BopD; d.b_ldb = 768;
        d.cm = Smir; d.c_os = 512;
        d.gz_main = 1;
        d.xa = G; d.xb = Gt; d.xcm = G + MS; d.xcmT = Gt + MS;
        L(d, 4, 2, 512, 9, 2);
    }

    // 3) phase1 + init_carry + Kogge-Stone: ONE cooperative launch
    {
        ChainArgs ca;
        ca.Smir = Smir; ca.G = G; ca.Gt = Gt; ca.Qb = Qb; ca.Qtb = Qtb;
        ca.a0m = a0m; ca.a1m = a1m; ca.st0 = st0;
        void* kargs[] = { &ca };
        hipLaunchCooperativeKernel((void*)chain_k, dim3(256), dim3(256),
                                   kargs, 0, stream);
    }
    // after 7 KS rounds (odd number of swaps): final carries in a1m

    // 4) fused phase3 + obs
    p3obs_k<<<dim3(1, 64, 8), dim3(512), 0, stream>>>(
        a1m, G, Smir, BopO, Vn, states, obs);
}

// Round 15
// 703.254 us; speedup vs baseline: 2.3534x; 2.3534x over previous
//
#include <hip/hip_runtime.h>
#include <hip/hip_bf16.h>

// ---------------------------------------------------------------------------
// LinearSystem: chunked parallel scan (128 chunks x 8 steps), bf16 MFMA.
// Round 15 = exact revert to Round 8 (best measured: 703us). R9-R14 variants
// (phase1 restructures, re-chunking, persistent scan, p3obs double-buffer,
// cooperative fusion) all regressed; this configuration is the local optimum.
// ---------------------------------------------------------------------------

typedef short bfrag __attribute__((ext_vector_type(8)));   // 8 x bf16 bits
typedef float f32x4 __attribute__((ext_vector_type(4)));

__device__ __host__ inline unsigned short f2bf(float f) {
    union { float f; unsigned u; } x; x.f = f;
    unsigned r = x.u + 0x7fffu + ((x.u >> 16) & 1u);   // RNE
    return (unsigned short)(r >> 16);
}
__device__ inline float bf2f(unsigned short h) {
    union { unsigned u; float f; } x; x.u = ((unsigned)h) << 16;
    return x.f;
}

#define MSL 262144L   // 512*512 matrix stride

struct GemmDesc {
    const unsigned short* a0; const unsigned short* a1;  // A (k < ksplit -> a0)
    const unsigned short* b;                 // B, bf16, (N,K) row-major (B^T)
    float* c;                                // f32 C out (nullable)
    const unsigned short* cmbeta;            // bf16 beta source (beta==2)
    unsigned short* cm;                      // bf16 mirror out (nullable)
    unsigned short* cmT;                     // bf16 transposed mirror (512x512)
    long a0_base, a0_os, a0_is;              // row map: (r>>icl)*os + (r&mask)*is
    long a1_base, a1_os, a1_is;
    long a_zq, a_zr;
    long b_base, b_ldb, b_zq, b_zr;
    long c_base, c_os, c_is, c_zq, c_zr;
    long cm_base, cmb_base, cmT_base;
    long a_shift;                            // prefix rows (copy-only, acc=0)
    int a0_icl, a1_icl, c_icl, zdivl;
    int ksplit, K, beta;                     // beta: 0 none, 2 bf16 cmbeta
    int gxl, gyl, gz_main;
    // aux power-chain slice (bz >= gz_main): 512x512 C = xa[z] @ xb^T
    const unsigned short* xa; const unsigned short* xb;
    unsigned short* xcm; unsigned short* xcmT;
};

// 128x128 tile, BK=64, 4 waves (2x2 of 64x64), double-buffered 2-phase.
__global__ __launch_bounds__(256) void gemm_k(GemmDesc d) {
    __shared__ __align__(16) unsigned short As[2][128 * 64];
    __shared__ __align__(16) unsigned short Bs[2][128 * 64];
    const int tid  = threadIdx.x;
    const int lane = tid & 63;
    const int w    = tid >> 6;
    const int wrow = (w >> 1) * 64, wcol = (w & 1) * 64;

    // flattened grid + XCD-chunked bijective swizzle (x fastest)
    const unsigned nx = gridDim.x, ny = gridDim.y;
    const unsigned nwg = nx * ny * gridDim.z;
    unsigned wid = blockIdx.x + nx * (blockIdx.y + ny * blockIdx.z);
    if ((nwg & 7) == 0) wid = (wid & 7) * (nwg >> 3) + (wid >> 3);
    const int bx = wid & (nx - 1);
    const int by = (wid >> d.gxl) & (ny - 1);
    int bz = wid >> (d.gxl + d.gyl);

    if (bz >= d.gz_main) {                   // aux: 512x512 power-chain GEMM
        if (by >= 4) return;
        const long za = (long)(bz - d.gz_main) * MSL;
        d.a0 = d.xa; d.a0_base = za; d.a0_os = 512; d.a0_is = 0; d.a0_icl = 0;
        d.a1 = nullptr;
        d.b = d.xb; d.b_base = 0; d.b_ldb = 512; d.b_zq = d.b_zr = 0;
        d.K = 512; d.ksplit = 1 << 30; d.beta = 0; d.a_shift = 0;
        d.a_zq = d.a_zr = 0;
        d.c = nullptr; d.cm = d.xcm; d.cm_base = za;
        d.c_os = 512; d.c_is = 0; d.c_icl = 0; d.c_zq = d.c_zr = 0; d.c_base = 0;
        d.cmT = d.xcmT; d.cmT_base = za;
        bz = 0;
    }
    const long zq = (long)bz >> d.zdivl;
    const long zr = (long)bz & ((1L << d.zdivl) - 1);
    const int row0 = by * 128;
    const int col0 = bx * 128;

    const int g_r = tid >> 3;                // staging row within 32-row group
    const int g_k = (tid & 7) * 8;           // 16B k-slot
    const int swz = (g_r & 7) << 3;          // XOR swizzle (8-elem units)
    const long za_ = zq * d.a_zq + zr * d.a_zr;
    const long zb_ = zq * d.b_zq + zr * d.b_zr;

    const long m0a = (1L << d.a0_icl) - 1, m1a = (1L << d.a1_icl) - 1;
    long a0off[4], a1off[4], boff[4];
#pragma unroll
    for (int i = 0; i < 4; ++i) {
        long ar = (long)row0 + i * 32 + g_r - d.a_shift;
        if (ar < 0) ar = 0;
        a0off[i] = d.a0_base + za_ + (ar >> d.a0_icl) * d.a0_os + (ar & m0a) * d.a0_is;
        a1off[i] = d.a1 ? (d.a1_base + za_ + (ar >> d.a1_icl) * d.a1_os + (ar & m1a) * d.a1_is) : 0;
        boff[i]  = d.b_base + zb_ + (long)(col0 + i * 32 + g_r) * d.b_ldb;
    }

    bfrag ar_[4], br_[4];
    auto LOADT = [&](int t) {
        const int k0 = t * 64;
        const bool s1 = (k0 >= d.ksplit);
        const int kb = (s1 ? k0 - d.ksplit : k0) + g_k;
        const unsigned short* sp = s1 ? d.a1 : d.a0;
#pragma unroll
        for (int i = 0; i < 4; ++i)
            ar_[i] = *(const bfrag*)(sp + (s1 ? a1off[i] : a0off[i]) + kb);
#pragma unroll
        for (int i = 0; i < 4; ++i) br_[i] = *(const bfrag*)(d.b + boff[i] + k0 + g_k);
    };
    auto WRT = [&](int buf) {
#pragma unroll
        for (int i = 0; i < 4; ++i) {
            *(bfrag*)&As[buf][(i * 32 + g_r) * 64 + (g_k ^ swz)] = ar_[i];
            *(bfrag*)&Bs[buf][(i * 32 + g_r) * 64 + (g_k ^ swz)] = br_[i];
        }
    };

    f32x4 acc[4][4] = {};
    const int nt = d.K / 64;

    LOADT(0); WRT(0); __syncthreads();
    int cur = 0;
    for (int t = 0; t < nt; ++t) {
        if (t + 1 < nt) LOADT(t + 1);        // issue next-tile loads early
#pragma unroll
        for (int ks = 0; ks < 2; ++ks) {
            const int kk = ks * 32 + (lane >> 4) * 8;
            bfrag af[4], bf_[4];
#pragma unroll
            for (int mt = 0; mt < 4; ++mt) {
                const int r = wrow + mt * 16 + (lane & 15);
                af[mt] = *(const bfrag*)&As[cur][r * 64 + (kk ^ ((r & 7) << 3))];
            }
#pragma unroll
            for (int nn = 0; nn < 4; ++nn) {
                const int r = wcol + nn * 16 + (lane & 15);
                bf_[nn] = *(const bfrag*)&Bs[cur][r * 64 + (kk ^ ((r & 7) << 3))];
            }
#pragma unroll
            for (int mt = 0; mt < 4; ++mt)
#pragma unroll
                for (int nn = 0; nn < 4; ++nn)
                    acc[mt][nn] = __builtin_amdgcn_mfma_f32_16x16x32_bf16(
                        af[mt], bf_[nn], acc[mt][nn], 0, 0, 0);
        }
        if (t + 1 < nt) WRT(cur ^ 1);        // write-late (hidden under compute)
        __syncthreads();                     // ONE barrier per K-step
        cur ^= 1;
    }

    // ---- epilogue: C/D layout col=lane&15, row=(lane>>4)*4+j ----
    const long zc = zq * d.c_zq + zr * d.c_zr;
    const long mc = (1L << d.c_icl) - 1;
#pragma unroll
    for (int mt = 0; mt < 4; ++mt) {
        const int rb = row0 + wrow + mt * 16 + ((lane >> 4) << 2);
#pragma unroll
        for (int nn = 0; nn < 4; ++nn) {
            const int cc = col0 + wcol + nn * 16 + (lane & 15);
#pragma unroll
            for (int j = 0; j < 4; ++j) {
                const long r = rb + j;
                const long off = zc + (r >> d.c_icl) * d.c_os + (r & mc) * d.c_is + cc;
                float v = (r < d.a_shift) ? 0.0f : acc[mt][nn][j];
                if (d.beta == 2) v += bf2f(d.cmbeta[d.cmb_base + off]);
                if (d.c)  d.c[d.c_base + off] = v;
                if (d.cm) d.cm[d.cm_base + off] = f2bf(v);
                if (d.cmT) d.cmT[d.cmT_base + zc + (long)cc * 512 + r] = f2bf(v);
            }
        }
    }
}

// ---------------------------------------------------------------------------
// Fused phase3 + obs. Grid (1, 64, 8): by = 128-row tile (2 chunks x 64 b),
// z = k (step within chunk). 512 threads, 160 KiB LDS, 1 block/CU.
//   GEMM1: s[128x512] = carry @ (F^{k+1})^T + Smir_local; write states f32,
//          deposit bf16 rows into LDS Sb.
//   GEMM2: obs[128x256] = [Sb | cvt(Vn)] @ BopO^T; write obs f32.
// ---------------------------------------------------------------------------
__global__ __launch_bounds__(512) void p3obs_k(
        const unsigned short* __restrict__ carry, const unsigned short* __restrict__ Gm,
        const unsigned short* __restrict__ Smir, const unsigned short* __restrict__ BopO,
        const float* __restrict__ Vn, float* __restrict__ states, float* __restrict__ obs) {
    __shared__ __align__(16) unsigned char lds[163840];
    unsigned short* As1 = (unsigned short*)(lds);            // [128][64]  (phase A)
    unsigned short* Bs1 = (unsigned short*)(lds + 16384);    // [512][64]  (phase A)
    unsigned short* Sb  = (unsigned short*)(lds);            // [128][512] (phase B)
    unsigned short* A2  = (unsigned short*)(lds);            // [128][64]  (phase B2, over Sb)
    unsigned short* Ts  = (unsigned short*)(lds + 131072);   // [256][64]  (phase B)

    const int tid  = threadIdx.x;
    const int lane = tid & 63;
    const int w    = tid >> 6;               // 0..7
    const int wm   = w >> 2, wn = w & 3;     // 2 x 4 wave grid
    const int by   = blockIdx.y;             // 0..63
    const int k    = blockIdx.z;             // 0..7
    const unsigned short* G = Gm + (long)k * MSL;   // F^{k+1}, (512,512) row-major

    f32x4 acc[4][8] = {};

    // ---------- GEMM1 ----------
    for (int kt = 0; kt < 8; ++kt) {
        __syncthreads();
#pragma unroll
        for (int i = 0; i < 2; ++i) {        // A tile: carry rows
            const int fi = tid + i * 512;
            const int row = fi >> 3, kk = (fi & 7) * 8;
            const long rg = (long)by * 128 + row;
            const long c = rg >> 6, b = rg & 63;
            bfrag v = *(const bfrag*)(carry + c * 32768 + b * 512 + kt * 64 + kk);
            *(bfrag*)&As1[row * 64 + (kk ^ ((row & 7) << 3))] = v;
        }
#pragma unroll
        for (int i = 0; i < 8; ++i) {        // B tile: G rows (all 512)
            const int fi = tid + i * 512;
            const int row = fi >> 3, kk = (fi & 7) * 8;
            bfrag v = *(const bfrag*)(G + (long)row * 512 + kt * 64 + kk);
            *(bfrag*)&Bs1[row * 64 + (kk ^ ((row & 7) << 3))] = v;
        }
        __syncthreads();
#pragma unroll
        for (int ks = 0; ks < 2; ++ks) {
            const int kk = ks * 32 + (lane >> 4) * 8;
            bfrag af[4], bf_[8];
#pragma unroll
            for (int mt = 0; mt < 4; ++mt) {
                const int r = wm * 64 + mt * 16 + (lane & 15);
                af[mt] = *(const bfrag*)&As1[r * 64 + (kk ^ ((r & 7) << 3))];
            }
#pragma unroll
            for (int nt = 0; nt < 8; ++nt) {
                const int n = wn * 128 + nt * 16 + (lane & 15);
                bf_[nt] = *(const bfrag*)&Bs1[n * 64 + (kk ^ ((n & 7) << 3))];
            }
#pragma unroll
            for (int mt = 0; mt < 4; ++mt)
#pragma unroll
                for (int nt = 0; nt < 8; ++nt)
                    acc[mt][nt] = __builtin_amdgcn_mfma_f32_16x16x32_bf16(
                        af[mt], bf_[nt], acc[mt][nt], 0, 0, 0);
        }
    }
    __syncthreads();                          // As1/Bs1 dead; Sb about to be written

    // ---------- epilogue 1: +local, write states, build Sb ----------
#pragma unroll
    for (int mt = 0; mt < 4; ++mt) {
#pragma unroll
        for (int nt = 0; nt < 8; ++nt) {
#pragma unroll
            for (int j = 0; j < 4; ++j) {
                const int lr = wm * 64 + mt * 16 + ((lane >> 4) << 2) + j;
                const int cc = wn * 128 + nt * 16 + (lane & 15);
                const long rg = (long)by * 128 + lr;
                const long c = rg >> 6, b = rg & 63;
                const long t = c * 8 + k;
                float v = acc[mt][nt][j] + bf2f(Smir[b * 524288L + t * 512 + cc]);
                states[b * 524288L + t * 512 + cc] = v;
                Sb[lr * 512 + (cc ^ ((lr & 7) << 3))] = f2bf(v);
            }
        }
    }

    // ---------- GEMM2: obs = [Sb | Vn] @ BopO^T ----------
    f32x4 acc2[4][4] = {};
    for (int kt = 0; kt < 12; ++kt) {
        __syncthreads();
#pragma unroll
        for (int i = 0; i < 4; ++i) {        // Ts: BopO rows 0..255
            const int fi = tid + i * 512;
            const int row = fi >> 3, kk = (fi & 7) * 8;
            bfrag v = *(const bfrag*)(BopO + (long)row * 768 + kt * 64 + kk);
            *(bfrag*)&Ts[row * 64 + (kk ^ ((row & 7) << 3))] = v;
        }
        if (kt >= 8) {
#pragma unroll
            for (int i = 0; i < 2; ++i) {    // A2: Vn f32 -> bf16
                const int fi = tid + i * 512;
                const int row = fi >> 3, kk = (fi & 7) * 8;
                const long rg = (long)by * 128 + row;
                const long c = rg >> 6, b = rg & 63;
                const long t = c * 8 + k;
                const float* p = Vn + b * 262144L + t * 256 + (kt - 8) * 64 + kk;
                f32x4 x0 = *(const f32x4*)p, x1 = *(const f32x4*)(p + 4);
                union { bfrag v; unsigned short h[8]; } u;
#pragma unroll
                for (int q = 0; q < 4; ++q) { u.h[q] = f2bf(x0[q]); u.h[4 + q] = f2bf(x1[q]); }
                *(bfrag*)&A2[row * 64 + (kk ^ ((row & 7) << 3))] = u.v;
            }
        }
        __syncthreads();
#pragma unroll
        for (int ks = 0; ks < 2; ++ks) {
            const int kk = ks * 32 + (lane >> 4) * 8;
            bfrag af[4], bf_[4];
#pragma unroll
            for (int mt = 0; mt < 4; ++mt) {
                const int r = wm * 64 + mt * 16 + (lane & 15);
                af[mt] = (kt < 8)
                    ? *(const bfrag*)&Sb[r * 512 + ((kt * 64 + kk) ^ ((r & 7) << 3))]
                    : *(const bfrag*)&A2[r * 64 + (kk ^ ((r & 7) << 3))];
            }
#pragma unroll
            for (int nt = 0; nt < 4; ++nt) {
                const int n = wn * 64 + nt * 16 + (lane & 15);
                bf_[nt] = *(const bfrag*)&Ts[n * 64 + (kk ^ ((n & 7) << 3))];
            }
#pragma unroll
            for (int mt = 0; mt < 4; ++mt)
#pragma unroll
                for (int nt = 0; nt < 4; ++nt)
                    acc2[mt][nt] = __builtin_amdgcn_mfma_f32_16x16x32_bf16(
                        af[mt], bf_[nt], acc2[mt][nt], 0, 0, 0);
        }
    }
    // ---------- epilogue 2: write obs ----------
#pragma unroll
    for (int mt = 0; mt < 4; ++mt) {
#pragma unroll
        for (int nt = 0; nt < 4; ++nt) {
#pragma unroll
            for (int j = 0; j < 4; ++j) {
                const int lr = wm * 64 + mt * 16 + ((lane >> 4) << 2) + j;
                const int cc = wn * 64 + nt * 16 + (lane & 15);
                const long rg = (long)by * 128 + lr;
                const long c = rg >> 6, b = rg & 63;
                const long t = c * 8 + k;
                obs[b * 262144L + t * 256 + cc] = acc2[mt][nt][j];
            }
        }
    }
}

// f32 -> bf16 bulk conversion, 8 elems/thread.
__global__ void cvt_k(const float* src, unsigned short* dst, long n) {
    long i = ((long)blockIdx.x * 256 + threadIdx.x) * 8;
    const long stride = (long)gridDim.x * 256 * 8;
    for (; i < n; i += stride) {
        f32x4 x0 = *(const f32x4*)(src + i), x1 = *(const f32x4*)(src + i + 4);
        union { bfrag v; unsigned short h[8]; } t;
#pragma unroll
        for (int q = 0; q < 4; ++q) { t.h[q] = f2bf(x0[q]); t.h[4 + q] = f2bf(x1[q]); }
        *(bfrag*)(dst + i) = t.v;
    }
}

// Build bf16 operators: BopD (512x768)=[B_mat|sqrt_S_W], BopO (256x768)=[H|sqrt_S_V],
// G[0]=F, Gt[0]=F^T.
__global__ void build_ops_k(const float* F, const float* Bm, const float* H,
                            const float* sW, const float* sV,
                            unsigned short* bopd, unsigned short* bopo,
                            unsigned short* G1, unsigned short* Gt1) {
    int i = blockIdx.x * 256 + threadIdx.x;
    const int n1 = 512 * 768, n2 = 256 * 768, n3 = 512 * 512;
    if (i < n1) { int n = i / 768, k = i % 768;
        bopd[i] = f2bf(k < 256 ? Bm[n * 256 + k] : sW[n * 512 + (k - 256)]); return; }
    i -= n1;
    if (i < n2) { int o = i / 768, k = i % 768;
        bopo[i] = f2bf(k < 512 ? H[o * 512 + k] : sV[o * 256 + (k - 512)]); return; }
    i -= n2;
    if (i < n3) { G1[i] = f2bf(F[i]); return; }
    i -= n3;
    if (i < n3) { int r = i / 512, c = i % 512; Gt1[i] = f2bf(F[c * 512 + r]); }
}

// Initial carries: dst[c*32768 + b*512 + s]; c==0 from st0 (f32), else from
// Smir local[c-1, 7] = Smir[b*524288 + (c-1)*4096 + 3584 + s].
__global__ void init_carry_k(const float* st0, const unsigned short* Smir,
                             unsigned short* dst) {
    const long i8 = ((long)blockIdx.x * 256 + threadIdx.x) * 8;  // 4,194,304 total
    if (i8 >= 4194304L) return;
    const long c = i8 >> 15, rem = i8 & 32767L;
    const long b = rem >> 9, s = rem & 511L;
    union { bfrag v; unsigned short h[8]; } t;
    if (c == 0) {
        const float* p = st0 + b * 512 + s;
        f32x4 x0 = *(const f32x4*)p, x1 = *(const f32x4*)(p + 4);
#pragma unroll
        for (int q = 0; q < 4; ++q) { t.h[q] = f2bf(x0[q]); t.h[4 + q] = f2bf(x1[q]); }
    } else {
        t.v = *(const bfrag*)(Smir + b * 524288L + (c - 1) * 4096L + 3584L + s);
    }
    *(bfrag*)(dst + i8) = t.v;
}

static GemmDesc D0() {
    GemmDesc d = {};
    d.zdivl = 30;
    d.ksplit = 1 << 30;
    d.b_ldb = 512; d.K = 512;
    d.gz_main = 1 << 30;
    return d;
}

extern "C" void kernel_launch(void* const* d_in, const int* in_sizes, int n_in,
                              void* d_out, int out_size, void* d_ws, size_t ws_size,
                              hipStream_t stream) {
    const float* st0 = (const float*)d_in[0];
    const float* inp = (const float*)d_in[1];
    const float* Wn  = (const float*)d_in[2];
    const float* Vn  = (const float*)d_in[3];
    const float* F   = (const float*)d_in[4];
    const float* Bm  = (const float*)d_in[5];
    const float* H   = (const float*)d_in[6];
    const float* sW  = (const float*)d_in[7];
    const float* sV  = (const float*)d_in[8];

    float* states = (float*)d_out;              // (64,1024,512) f32
    float* obs    = states + 33554432L;         // (64,1024,256) f32

    const long MS = MSL;
    const long CB = 32768;    // 64*512 per-chunk carry block
    const int  NC = 128;      // chunks
    const int  CL = 8;        // chunk length
    const long TOS = 524288;  // batch stride (1024*512)
    const long COS = (long)CL * 512;   // chunk stride = 4096

    // d_out states region: inp/Wn bf16 scratch (dead after drive; p3obs writes
    // states only at the very end).
    unsigned short* inpb = (unsigned short*)states;
    unsigned short* Wnb  = inpb + 16777216L;

    // ws layout (all bf16 bits)
    unsigned short* Smir = (unsigned short*)d_ws;          // 33,554,432
    unsigned short* G    = Smir + 33554432L;               // G[j]=F^{j+1}, j=0..7
    unsigned short* Gt   = G + 8 * MS;
    unsigned short* Qb   = Gt + 8 * MS;                    // F^{16*2^j}, j=0..5
    unsigned short* Qtb  = Qb + 6 * MS;                    // j=0..4 (+1 spare)
    unsigned short* BopD = Qtb + 6 * MS;                   // 512*768
    unsigned short* BopO = BopD + 512 * 768;               // 256*768
    unsigned short* a0m  = BopO + 256 * 768;               // NC*CB carries
    unsigned short* a1m  = a0m + (long)NC * CB;
    (void)in_sizes; (void)n_in; (void)out_size; (void)ws_size;

    auto L = [&](const GemmDesc& d, int gx, int gxl, int gy, int gyl, int gz) {
        GemmDesc dd = d; dd.gxl = gxl; dd.gyl = gyl;
        gemm_k<<<dim3(gx, gy, gz), dim3(256), 0, stream>>>(dd);
    };

    // 0) bf16 prepass: inp, Wn -> d_out scratch
    cvt_k<<<dim3(2048), dim3(256), 0, stream>>>(inp, inpb, 16777216L);
    cvt_k<<<dim3(2048), dim3(256), 0, stream>>>(Wn, Wnb, 33554432L);

    // 1) operators + F, F^T
    build_ops_k<<<dim3(4352), dim3(256), 0, stream>>>(F, Bm, H, sW, sV, BopD, BopO, G, Gt);

    // 2) drive = [inputs | W_noise] @ BopD^T -> Smir (all-bf16)
    {
        GemmDesc d = D0();
        d.a0 = inpb; d.a0_os = 256;
        d.a1 = Wnb;  d.a1_os = 512;
        d.ksplit = 256; d.K = 768;
        d.b = BopD; d.b_ldb = 768;
        d.cm = Smir; d.c_os = 512;
        L(d, 4, 2, 512, 9, 1);
    }

    // 3) phase 1 (7 sequential steps) with fused power-chain aux slices
    //    aux k=1: G[1]; k=2: G[2..3]; k=3: G[4..7]; k=4..7: Qb[0..3] (+T)
    for (int k = 1; k < CL; ++k) {
        GemmDesc d = D0();
        d.a0 = Smir; d.a0_base = (long)(k - 1) * 512;
        d.a0_icl = 7; d.a0_is = COS; d.a0_os = TOS;
        d.b = G;  // F
        d.c_base = (long)k * 512;
        d.c_icl = 7; d.c_is = COS; d.c_os = TOS;
        d.beta = 2; d.cmbeta = Smir; d.cmb_base = (long)k * 512;
        d.cm = Smir; d.cm_base = (long)k * 512;
        d.gz_main = 1;
        int n;
        if (k == 1)      { d.xa = G;           d.xb = Gt;           d.xcm = G + MS;      d.xcmT = Gt + MS;      n = 1; }
        else if (k == 2) { d.xa = G;           d.xb = Gt + MS;      d.xcm = G + 2 * MS;  d.xcmT = Gt + 2 * MS;  n = 2; }
        else if (k == 3) { d.xa = G;           d.xb = Gt + 3 * MS;  d.xcm = G + 4 * MS;  d.xcmT = Gt + 4 * MS;  n = 4; }
        else if (k == 4) { d.xa = G + 7 * MS;  d.xb = Gt + 7 * MS;  d.xcm = Qb;          d.xcmT = Qtb;          n = 1; }
        else             { int j = k - 5;
                           d.xa = Qb + j * MS; d.xb = Qtb + j * MS; d.xcm = Qb + (j+1)*MS; d.xcmT = Qtb + (j+1)*MS; n = 1; }
        L(d, 4, 2, 64, 6, 1 + n);
    }

    // 4) initial carries a[c]
    init_carry_k<<<dim3(2048), dim3(256), 0, stream>>>(st0, Smir, a0m);

    // 5) Kogge-Stone (bf16 carries): nxt[r] = cur[r] + (r>=s*64 ? cur[r-s*64]@(F^{8s})^T : 0)
    //    aux s=1: Qb[4]=F^256 (+T); s=2: Qb[5]=F^512
    unsigned short* curm = a0m;
    unsigned short* nxtm = a1m;
    for (int s = 1; s < NC; s <<= 1) {
        GemmDesc d = D0();
        d.a0 = curm; d.a0_os = 512;
        d.a_shift = (long)s * 64;
        if (s == 1) { d.b = G + 7 * MS; }
        else        { d.b = Qb + (long)(__builtin_ctz(s) - 1) * MS; }
        d.beta = 2; d.cmbeta = curm; d.cmb_base = 0;
        d.cm = nxtm; d.c_os = 512;
        int n = 0;
        if (s == 1) { d.gz_main = 1; d.xa = Qb + 3 * MS; d.xb = Qtb + 3 * MS;
                      d.xcm = Qb + 4 * MS; d.xcmT = Qtb + 4 * MS; n = 1; }
        if (s == 2) { d.gz_main = 1; d.xa = Qb + 4 * MS; d.xb = Qtb + 4 * MS;
                      d.xcm = Qb + 5 * MS; d.xcmT = nullptr; n = 1; }
        L(d, 4, 2, 64, 6, 1 + n);
        unsigned short* tm = curm; curm = nxtm; nxtm = tm;
    }
    // after 7 rounds: curm = a1m

    // 6) fused phase3 + obs
    p3obs_k<<<dim3(1, 64, 8), dim3(512), 0, stream>>>(
        curm, G, Smir, BopO, Vn, states, obs);
}

// Round 16
// 651.081 us; speedup vs baseline: 2.5420x; 1.0801x over previous
//
#include <hip/hip_runtime.h>
#include <hip/hip_bf16.h>

// ---------------------------------------------------------------------------
// LinearSystem: chunked parallel scan (128 chunks x 8 steps), bf16 MFMA.
// Round 16 = R8/R15 (best, 703us) with ONE change: gemm_k templated on BM;
// the 14 latency-bound chain launches (phase1 x7, KS x7) use BM=64 tiles
// (512+ blocks -> 2 blocks/CU = 2 waves/SIMD, vs 1 before). Drive keeps
// BM=128; p3obs_k untouched.
// ---------------------------------------------------------------------------

typedef short bfrag __attribute__((ext_vector_type(8)));   // 8 x bf16 bits
typedef float f32x4 __attribute__((ext_vector_type(4)));

__device__ __host__ inline unsigned short f2bf(float f) {
    union { float f; unsigned u; } x; x.f = f;
    unsigned r = x.u + 0x7fffu + ((x.u >> 16) & 1u);   // RNE
    return (unsigned short)(r >> 16);
}
__device__ inline float bf2f(unsigned short h) {
    union { unsigned u; float f; } x; x.u = ((unsigned)h) << 16;
    return x.f;
}

#define MSL 262144L   // 512*512 matrix stride

struct GemmDesc {
    const unsigned short* a0; const unsigned short* a1;  // A (k < ksplit -> a0)
    const unsigned short* b;                 // B, bf16, (N,K) row-major (B^T)
    float* c;                                // f32 C out (nullable)
    const unsigned short* cmbeta;            // bf16 beta source (beta==2)
    unsigned short* cm;                      // bf16 mirror out (nullable)
    unsigned short* cmT;                     // bf16 transposed mirror (512x512)
    long a0_base, a0_os, a0_is;              // row map: (r>>icl)*os + (r&mask)*is
    long a1_base, a1_os, a1_is;
    long a_zq, a_zr;
    long b_base, b_ldb, b_zq, b_zr;
    long c_base, c_os, c_is, c_zq, c_zr;
    long cm_base, cmb_base, cmT_base;
    long a_shift;                            // prefix rows (copy-only, acc=0)
    int a0_icl, a1_icl, c_icl, zdivl;
    int ksplit, K, beta;                     // beta: 0 none, 2 bf16 cmbeta
    int gxl, gyl, gz_main;
    // aux power-chain slice (bz >= gz_main): 512x512 C = xa[z] @ xb^T
    const unsigned short* xa; const unsigned short* xb;
    unsigned short* xcm; unsigned short* xcmT;
};

// BM x 128 tile, BK=64, 4 waves (2x2; wave tile (BM/2) x 64), 2-phase dbuf.
template<int BM>
__global__ __launch_bounds__(256) void gemm_k(GemmDesc d) {
    constexpr int MT = BM / 32;              // row frags per wave; also A issues
    __shared__ __align__(16) unsigned short As[2][BM * 64];
    __shared__ __align__(16) unsigned short Bs[2][128 * 64];
    const int tid  = threadIdx.x;
    const int lane = tid & 63;
    const int w    = tid >> 6;
    const int wrow = (w >> 1) * (BM / 2), wcol = (w & 1) * 64;

    // flattened grid + XCD-chunked bijective swizzle (x fastest)
    const unsigned nx = gridDim.x, ny = gridDim.y;
    const unsigned nwg = nx * ny * gridDim.z;
    unsigned wid = blockIdx.x + nx * (blockIdx.y + ny * blockIdx.z);
    if ((nwg & 7) == 0) wid = (wid & 7) * (nwg >> 3) + (wid >> 3);
    const int bx = wid & (nx - 1);
    const int by = (wid >> d.gxl) & (ny - 1);
    int bz = wid >> (d.gxl + d.gyl);

    if (bz >= d.gz_main) {                   // aux: 512x512 power-chain GEMM
        if (by >= (512 / BM)) return;
        const long za = (long)(bz - d.gz_main) * MSL;
        d.a0 = d.xa; d.a0_base = za; d.a0_os = 512; d.a0_is = 0; d.a0_icl = 0;
        d.a1 = nullptr;
        d.b = d.xb; d.b_base = 0; d.b_ldb = 512; d.b_zq = d.b_zr = 0;
        d.K = 512; d.ksplit = 1 << 30; d.beta = 0; d.a_shift = 0;
        d.a_zq = d.a_zr = 0;
        d.c = nullptr; d.cm = d.xcm; d.cm_base = za;
        d.c_os = 512; d.c_is = 0; d.c_icl = 0; d.c_zq = d.c_zr = 0; d.c_base = 0;
        d.cmT = d.xcmT; d.cmT_base = za;
        bz = 0;
    }
    const long zq = (long)bz >> d.zdivl;
    const long zr = (long)bz & ((1L << d.zdivl) - 1);
    const int row0 = by * BM;
    const int col0 = bx * 128;

    const int g_r = tid >> 3;                // staging row within 32-row group
    const int g_k = (tid & 7) * 8;           // 16B k-slot
    const int swz = (g_r & 7) << 3;          // XOR swizzle (8-elem units)
    const long za_ = zq * d.a_zq + zr * d.a_zr;
    const long zb_ = zq * d.b_zq + zr * d.b_zr;

    const long m0a = (1L << d.a0_icl) - 1, m1a = (1L << d.a1_icl) - 1;
    long a0off[MT], a1off[MT], boff[4];
#pragma unroll
    for (int i = 0; i < MT; ++i) {
        long ar = (long)row0 + i * 32 + g_r - d.a_shift;
        if (ar < 0) ar = 0;
        a0off[i] = d.a0_base + za_ + (ar >> d.a0_icl) * d.a0_os + (ar & m0a) * d.a0_is;
        a1off[i] = d.a1 ? (d.a1_base + za_ + (ar >> d.a1_icl) * d.a1_os + (ar & m1a) * d.a1_is) : 0;
    }
#pragma unroll
    for (int i = 0; i < 4; ++i)
        boff[i] = d.b_base + zb_ + (long)(col0 + i * 32 + g_r) * d.b_ldb;

    bfrag ar_[MT], br_[4];
    auto LOADT = [&](int t) {
        const int k0 = t * 64;
        const bool s1 = (k0 >= d.ksplit);
        const int kb = (s1 ? k0 - d.ksplit : k0) + g_k;
        const unsigned short* sp = s1 ? d.a1 : d.a0;
#pragma unroll
        for (int i = 0; i < MT; ++i)
            ar_[i] = *(const bfrag*)(sp + (s1 ? a1off[i] : a0off[i]) + kb);
#pragma unroll
        for (int i = 0; i < 4; ++i) br_[i] = *(const bfrag*)(d.b + boff[i] + k0 + g_k);
    };
    auto WRT = [&](int buf) {
#pragma unroll
        for (int i = 0; i < MT; ++i)
            *(bfrag*)&As[buf][(i * 32 + g_r) * 64 + (g_k ^ swz)] = ar_[i];
#pragma unroll
        for (int i = 0; i < 4; ++i)
            *(bfrag*)&Bs[buf][(i * 32 + g_r) * 64 + (g_k ^ swz)] = br_[i];
    };

    f32x4 acc[MT][4] = {};
    const int nt = d.K / 64;

    LOADT(0); WRT(0); __syncthreads();
    int cur = 0;
    for (int t = 0; t < nt; ++t) {
        if (t + 1 < nt) LOADT(t + 1);        // issue next-tile loads early
#pragma unroll
        for (int ks = 0; ks < 2; ++ks) {
            const int kk = ks * 32 + (lane >> 4) * 8;
            bfrag af[MT], bf_[4];
#pragma unroll
            for (int mt = 0; mt < MT; ++mt) {
                const int r = wrow + mt * 16 + (lane & 15);
                af[mt] = *(const bfrag*)&As[cur][r * 64 + (kk ^ ((r & 7) << 3))];
            }
#pragma unroll
            for (int nn = 0; nn < 4; ++nn) {
                const int r = wcol + nn * 16 + (lane & 15);
                bf_[nn] = *(const bfrag*)&Bs[cur][r * 64 + (kk ^ ((r & 7) << 3))];
            }
#pragma unroll
            for (int mt = 0; mt < MT; ++mt)
#pragma unroll
                for (int nn = 0; nn < 4; ++nn)
                    acc[mt][nn] = __builtin_amdgcn_mfma_f32_16x16x32_bf16(
                        af[mt], bf_[nn], acc[mt][nn], 0, 0, 0);
        }
        if (t + 1 < nt) WRT(cur ^ 1);        // write-late (hidden under compute)
        __syncthreads();                     // ONE barrier per K-step
        cur ^= 1;
    }

    // ---- epilogue: C/D layout col=lane&15, row=(lane>>4)*4+j ----
    const long zc = zq * d.c_zq + zr * d.c_zr;
    const long mc = (1L << d.c_icl) - 1;
#pragma unroll
    for (int mt = 0; mt < MT; ++mt) {
        const int rb = row0 + wrow + mt * 16 + ((lane >> 4) << 2);
#pragma unroll
        for (int nn = 0; nn < 4; ++nn) {
            const int cc = col0 + wcol + nn * 16 + (lane & 15);
#pragma unroll
            for (int j = 0; j < 4; ++j) {
                const long r = rb + j;
                const long off = zc + (r >> d.c_icl) * d.c_os + (r & mc) * d.c_is + cc;
                float v = (r < d.a_shift) ? 0.0f : acc[mt][nn][j];
                if (d.beta == 2) v += bf2f(d.cmbeta[d.cmb_base + off]);
                if (d.c)  d.c[d.c_base + off] = v;
                if (d.cm) d.cm[d.cm_base + off] = f2bf(v);
                if (d.cmT) d.cmT[d.cmT_base + zc + (long)cc * 512 + r] = f2bf(v);
            }
        }
    }
}

// ---------------------------------------------------------------------------
// Fused phase3 + obs (R8 version, unchanged). Grid (1, 64, 8), 512 thr.
// ---------------------------------------------------------------------------
__global__ __launch_bounds__(512) void p3obs_k(
        const unsigned short* __restrict__ carry, const unsigned short* __restrict__ Gm,
        const unsigned short* __restrict__ Smir, const unsigned short* __restrict__ BopO,
        const float* __restrict__ Vn, float* __restrict__ states, float* __restrict__ obs) {
    __shared__ __align__(16) unsigned char lds[163840];
    unsigned short* As1 = (unsigned short*)(lds);            // [128][64]  (phase A)
    unsigned short* Bs1 = (unsigned short*)(lds + 16384);    // [512][64]  (phase A)
    unsigned short* Sb  = (unsigned short*)(lds);            // [128][512] (phase B)
    unsigned short* A2  = (unsigned short*)(lds);            // [128][64]  (B2, over Sb)
    unsigned short* Ts  = (unsigned short*)(lds + 131072);   // [256][64]  (phase B)

    const int tid  = threadIdx.x;
    const int lane = tid & 63;
    const int w    = tid >> 6;               // 0..7
    const int wm   = w >> 2, wn = w & 3;     // 2 x 4 wave grid
    const int by   = blockIdx.y;             // 0..63
    const int k    = blockIdx.z;             // 0..7
    const unsigned short* G = Gm + (long)k * MSL;   // F^{k+1}

    f32x4 acc[4][8] = {};

    // ---------- GEMM1 ----------
    for (int kt = 0; kt < 8; ++kt) {
        __syncthreads();
#pragma unroll
        for (int i = 0; i < 2; ++i) {        // A tile: carry rows
            const int fi = tid + i * 512;
            const int row = fi >> 3, kk = (fi & 7) * 8;
            const long rg = (long)by * 128 + row;
            const long c = rg >> 6, b = rg & 63;
            bfrag v = *(const bfrag*)(carry + c * 32768 + b * 512 + kt * 64 + kk);
            *(bfrag*)&As1[row * 64 + (kk ^ ((row & 7) << 3))] = v;
        }
#pragma unroll
        for (int i = 0; i < 8; ++i) {        // B tile: G rows (all 512)
            const int fi = tid + i * 512;
            const int row = fi >> 3, kk = (fi & 7) * 8;
            bfrag v = *(const bfrag*)(G + (long)row * 512 + kt * 64 + kk);
            *(bfrag*)&Bs1[row * 64 + (kk ^ ((row & 7) << 3))] = v;
        }
        __syncthreads();
#pragma unroll
        for (int ks = 0; ks < 2; ++ks) {
            const int kk = ks * 32 + (lane >> 4) * 8;
            bfrag af[4], bf_[8];
#pragma unroll
            for (int mt = 0; mt < 4; ++mt) {
                const int r = wm * 64 + mt * 16 + (lane & 15);
                af[mt] = *(const bfrag*)&As1[r * 64 + (kk ^ ((r & 7) << 3))];
            }
#pragma unroll
            for (int nt = 0; nt < 8; ++nt) {
                const int n = wn * 128 + nt * 16 + (lane & 15);
                bf_[nt] = *(const bfrag*)&Bs1[n * 64 + (kk ^ ((n & 7) << 3))];
            }
#pragma unroll
            for (int mt = 0; mt < 4; ++mt)
#pragma unroll
                for (int nt = 0; nt < 8; ++nt)
                    acc[mt][nt] = __builtin_amdgcn_mfma_f32_16x16x32_bf16(
                        af[mt], bf_[nt], acc[mt][nt], 0, 0, 0);
        }
    }
    __syncthreads();                          // As1/Bs1 dead; Sb about to be written

    // ---------- epilogue 1: +local, write states, build Sb ----------
#pragma unroll
    for (int mt = 0; mt < 4; ++mt) {
#pragma unroll
        for (int nt = 0; nt < 8; ++nt) {
#pragma unroll
            for (int j = 0; j < 4; ++j) {
                const int lr = wm * 64 + mt * 16 + ((lane >> 4) << 2) + j;
                const int cc = wn * 128 + nt * 16 + (lane & 15);
                const long rg = (long)by * 128 + lr;
                const long c = rg >> 6, b = rg & 63;
                const long t = c * 8 + k;
                float v = acc[mt][nt][j] + bf2f(Smir[b * 524288L + t * 512 + cc]);
                states[b * 524288L + t * 512 + cc] = v;
                Sb[lr * 512 + (cc ^ ((lr & 7) << 3))] = f2bf(v);
            }
        }
    }

    // ---------- GEMM2: obs = [Sb | cvt(Vn)] @ BopO^T ----------
    f32x4 acc2[4][4] = {};
    for (int kt = 0; kt < 12; ++kt) {
        __syncthreads();
#pragma unroll
        for (int i = 0; i < 4; ++i) {        // Ts: BopO rows 0..255
            const int fi = tid + i * 512;
            const int row = fi >> 3, kk = (fi & 7) * 8;
            bfrag v = *(const bfrag*)(BopO + (long)row * 768 + kt * 64 + kk);
            *(bfrag*)&Ts[row * 64 + (kk ^ ((row & 7) << 3))] = v;
        }
        if (kt >= 8) {
#pragma unroll
            for (int i = 0; i < 2; ++i) {    // A2: Vn f32 -> bf16
                const int fi = tid + i * 512;
                const int row = fi >> 3, kk = (fi & 7) * 8;
                const long rg = (long)by * 128 + row;
                const long c = rg >> 6, b = rg & 63;
                const long t = c * 8 + k;
                const float* p = Vn + b * 262144L + t * 256 + (kt - 8) * 64 + kk;
                f32x4 x0 = *(const f32x4*)p, x1 = *(const f32x4*)(p + 4);
                union { bfrag v; unsigned short h[8]; } u;
#pragma unroll
                for (int q = 0; q < 4; ++q) { u.h[q] = f2bf(x0[q]); u.h[4 + q] = f2bf(x1[q]); }
                *(bfrag*)&A2[row * 64 + (kk ^ ((row & 7) << 3))] = u.v;
            }
        }
        __syncthreads();
#pragma unroll
        for (int ks = 0; ks < 2; ++ks) {
            const int kk = ks * 32 + (lane >> 4) * 8;
            bfrag af[4], bf_[4];
#pragma unroll
            for (int mt = 0; mt < 4; ++mt) {
                const int r = wm * 64 + mt * 16 + (lane & 15);
                af[mt] = (kt < 8)
                    ? *(const bfrag*)&Sb[r * 512 + ((kt * 64 + kk) ^ ((r & 7) << 3))]
                    : *(const bfrag*)&A2[r * 64 + (kk ^ ((r & 7) << 3))];
            }
#pragma unroll
            for (int nt = 0; nt < 4; ++nt) {
                const int n = wn * 64 + nt * 16 + (lane & 15);
                bf_[nt] = *(const bfrag*)&Ts[n * 64 + (kk ^ ((n & 7) << 3))];
            }
#pragma unroll
            for (int mt = 0; mt < 4; ++mt)
#pragma unroll
                for (int nt = 0; nt < 4; ++nt)
                    acc2[mt][nt] = __builtin_amdgcn_mfma_f32_16x16x32_bf16(
                        af[mt], bf_[nt], acc2[mt][nt], 0, 0, 0);
        }
    }
    // ---------- epilogue 2: write obs ----------
#pragma unroll
    for (int mt = 0; mt < 4; ++mt) {
#pragma unroll
        for (int nt = 0; nt < 4; ++nt) {
#pragma unroll
            for (int j = 0; j < 4; ++j) {
                const int lr = wm * 64 + mt * 16 + ((lane >> 4) << 2) + j;
                const int cc = wn * 64 + nt * 16 + (lane & 15);
                const long rg = (long)by * 128 + lr;
                const long c = rg >> 6, b = rg & 63;
                const long t = c * 8 + k;
                obs[b * 262144L + t * 256 + cc] = acc2[mt][nt][j];
            }
        }
    }
}

// f32 -> bf16 bulk conversion, 8 elems/thread.
__global__ void cvt_k(const float* src, unsigned short* dst, long n) {
    long i = ((long)blockIdx.x * 256 + threadIdx.x) * 8;
    const long stride = (long)gridDim.x * 256 * 8;
    for (; i < n; i += stride) {
        f32x4 x0 = *(const f32x4*)(src + i), x1 = *(const f32x4*)(src + i + 4);
        union { bfrag v; unsigned short h[8]; } t;
#pragma unroll
        for (int q = 0; q < 4; ++q) { t.h[q] = f2bf(x0[q]); t.h[4 + q] = f2bf(x1[q]); }
        *(bfrag*)(dst + i) = t.v;
    }
}

// Build bf16 operators: BopD (512x768)=[B_mat|sqrt_S_W], BopO (256x768)=[H|sqrt_S_V],
// G[0]=F, Gt[0]=F^T.
__global__ void build_ops_k(const float* F, const float* Bm, const float* H,
                            const float* sW, const float* sV,
                            unsigned short* bopd, unsigned short* bopo,
                            unsigned short* G1, unsigned short* Gt1) {
    int i = blockIdx.x * 256 + threadIdx.x;
    const int n1 = 512 * 768, n2 = 256 * 768, n3 = 512 * 512;
    if (i < n1) { int n = i / 768, k = i % 768;
        bopd[i] = f2bf(k < 256 ? Bm[n * 256 + k] : sW[n * 512 + (k - 256)]); return; }
    i -= n1;
    if (i < n2) { int o = i / 768, k = i % 768;
        bopo[i] = f2bf(k < 512 ? H[o * 512 + k] : sV[o * 256 + (k - 512)]); return; }
    i -= n2;
    if (i < n3) { G1[i] = f2bf(F[i]); return; }
    i -= n3;
    if (i < n3) { int r = i / 512, c = i % 512; Gt1[i] = f2bf(F[c * 512 + r]); }
}

// Initial carries: dst[c*32768 + b*512 + s]; c==0 from st0 (f32), else from
// Smir local[c-1, 7] = Smir[b*524288 + (c-1)*4096 + 3584 + s].
__global__ void init_carry_k(const float* st0, const unsigned short* Smir,
                             unsigned short* dst) {
    const long i8 = ((long)blockIdx.x * 256 + threadIdx.x) * 8;  // 4,194,304 total
    if (i8 >= 4194304L) return;
    const long c = i8 >> 15, rem = i8 & 32767L;
    const long b = rem >> 9, s = rem & 511L;
    union { bfrag v; unsigned short h[8]; } t;
    if (c == 0) {
        const float* p = st0 + b * 512 + s;
        f32x4 x0 = *(const f32x4*)p, x1 = *(const f32x4*)(p + 4);
#pragma unroll
        for (int q = 0; q < 4; ++q) { t.h[q] = f2bf(x0[q]); t.h[4 + q] = f2bf(x1[q]); }
    } else {
        t.v = *(const bfrag*)(Smir + b * 524288L + (c - 1) * 4096L + 3584L + s);
    }
    *(bfrag*)(dst + i8) = t.v;
}

static GemmDesc D0() {
    GemmDesc d = {};
    d.zdivl = 30;
    d.ksplit = 1 << 30;
    d.b_ldb = 512; d.K = 512;
    d.gz_main = 1 << 30;
    return d;
}

extern "C" void kernel_launch(void* const* d_in, const int* in_sizes, int n_in,
                              void* d_out, int out_size, void* d_ws, size_t ws_size,
                              hipStream_t stream) {
    const float* st0 = (const float*)d_in[0];
    const float* inp = (const float*)d_in[1];
    const float* Wn  = (const float*)d_in[2];
    const float* Vn  = (const float*)d_in[3];
    const float* F   = (const float*)d_in[4];
    const float* Bm  = (const float*)d_in[5];
    const float* H   = (const float*)d_in[6];
    const float* sW  = (const float*)d_in[7];
    const float* sV  = (const float*)d_in[8];

    float* states = (float*)d_out;              // (64,1024,512) f32
    float* obs    = states + 33554432L;         // (64,1024,256) f32

    const long MS = MSL;
    const long CB = 32768;    // 64*512 per-chunk carry block
    const int  NC = 128;      // chunks
    const int  CL = 8;        // chunk length
    const long TOS = 524288;  // batch stride (1024*512)
    const long COS = (long)CL * 512;   // chunk stride = 4096

    // d_out states region: inp/Wn bf16 scratch (dead after drive; p3obs writes
    // states only at the very end).
    unsigned short* inpb = (unsigned short*)states;
    unsigned short* Wnb  = inpb + 16777216L;

    // ws layout (all bf16 bits)
    unsigned short* Smir = (unsigned short*)d_ws;          // 33,554,432
    unsigned short* G    = Smir + 33554432L;               // G[j]=F^{j+1}, j=0..7
    unsigned short* Gt   = G + 8 * MS;
    unsigned short* Qb   = Gt + 8 * MS;                    // F^{16*2^j}, j=0..5
    unsigned short* Qtb  = Qb + 6 * MS;                    // j=0..4 (+1 spare)
    unsigned short* BopD = Qtb + 6 * MS;                   // 512*768
    unsigned short* BopO = BopD + 512 * 768;               // 256*768
    unsigned short* a0m  = BopO + 256 * 768;               // NC*CB carries
    unsigned short* a1m  = a0m + (long)NC * CB;
    (void)in_sizes; (void)n_in; (void)out_size; (void)ws_size;

    auto L128 = [&](const GemmDesc& d, int gx, int gxl, int gy, int gyl, int gz) {
        GemmDesc dd = d; dd.gxl = gxl; dd.gyl = gyl;
        gemm_k<128><<<dim3(gx, gy, gz), dim3(256), 0, stream>>>(dd);
    };
    auto L64 = [&](const GemmDesc& d, int gx, int gxl, int gy, int gyl, int gz) {
        GemmDesc dd = d; dd.gxl = gxl; dd.gyl = gyl;
        gemm_k<64><<<dim3(gx, gy, gz), dim3(256), 0, stream>>>(dd);
    };

    // 0) bf16 prepass: inp, Wn -> d_out scratch
    cvt_k<<<dim3(2048), dim3(256), 0, stream>>>(inp, inpb, 16777216L);
    cvt_k<<<dim3(2048), dim3(256), 0, stream>>>(Wn, Wnb, 33554432L);

    // 1) operators + F, F^T
    build_ops_k<<<dim3(4352), dim3(256), 0, stream>>>(F, Bm, H, sW, sV, BopD, BopO, G, Gt);

    // 2) drive = [inputs | W_noise] @ BopD^T -> Smir (all-bf16), BM=128
    {
        GemmDesc d = D0();
        d.a0 = inpb; d.a0_os = 256;
        d.a1 = Wnb;  d.a1_os = 512;
        d.ksplit = 256; d.K = 768;
        d.b = BopD; d.b_ldb = 768;
        d.cm = Smir; d.c_os = 512;
        L128(d, 4, 2, 512, 9, 1);
    }

    // 3) phase 1 (7 sequential steps, BM=64: 512 main blocks = 2/CU) with
    //    fused power-chain aux slices (aux now 32 blocks per matrix).
    //    aux k=1: G[1]; k=2: G[2..3]; k=3: G[4..7]; k=4..7: Qb[0..3] (+T)
    for (int k = 1; k < CL; ++k) {
        GemmDesc d = D0();
        d.a0 = Smir; d.a0_base = (long)(k - 1) * 512;
        d.a0_icl = 7; d.a0_is = COS; d.a0_os = TOS;
        d.b = G;  // F
        d.c_base = (long)k * 512;
        d.c_icl = 7; d.c_is = COS; d.c_os = TOS;
        d.beta = 2; d.cmbeta = Smir; d.cmb_base = (long)k * 512;
        d.cm = Smir; d.cm_base = (long)k * 512;
        d.gz_main = 1;
        int n;
        if (k == 1)      { d.xa = G;           d.xb = Gt;           d.xcm = G + MS;      d.xcmT = Gt + MS;      n = 1; }
        else if (k == 2) { d.xa = G;           d.xb = Gt + MS;      d.xcm = G + 2 * MS;  d.xcmT = Gt + 2 * MS;  n = 2; }
        else if (k == 3) { d.xa = G;           d.xb = Gt + 3 * MS;  d.xcm = G + 4 * MS;  d.xcmT = Gt + 4 * MS;  n = 4; }
        else if (k == 4) { d.xa = G + 7 * MS;  d.xb = Gt + 7 * MS;  d.xcm = Qb;          d.xcmT = Qtb;          n = 1; }
        else             { int j = k - 5;
                           d.xa = Qb + j * MS; d.xb = Qtb + j * MS; d.xcm = Qb + (j+1)*MS; d.xcmT = Qtb + (j+1)*MS; n = 1; }
        L64(d, 4, 2, 128, 7, 1 + n);
    }

    // 4) initial carries a[c]
    init_carry_k<<<dim3(2048), dim3(256), 0, stream>>>(st0, Smir, a0m);

    // 5) Kogge-Stone (bf16 carries, BM=64): nxt[r] = cur[r] +
    //    (r>=s*64 ? cur[r-s*64]@(F^{8s})^T : 0)
    //    aux s=1: Qb[4]=F^256 (+T); s=2: Qb[5]=F^512
    unsigned short* curm = a0m;
    unsigned short* nxtm = a1m;
    for (int s = 1; s < NC; s <<= 1) {
        GemmDesc d = D0();
        d.a0 = curm; d.a0_os = 512;
        d.a_shift = (long)s * 64;
        if (s == 1) { d.b = G + 7 * MS; }
        else        { d.b = Qb + (long)(__builtin_ctz(s) - 1) * MS; }
        d.beta = 2; d.cmbeta = curm; d.cmb_base = 0;
        d.cm = nxtm; d.c_os = 512;
        int n = 0;
        if (s == 1) { d.gz_main = 1; d.xa = Qb + 3 * MS; d.xb = Qtb + 3 * MS;
                      d.xcm = Qb + 4 * MS; d.xcmT = Qtb + 4 * MS; n = 1; }
        if (s == 2) { d.gz_main = 1; d.xa = Qb + 4 * MS; d.xb = Qtb + 4 * MS;
                      d.xcm = Qb + 5 * MS; d.xcmT = nullptr; n = 1; }
        L64(d, 4, 2, 128, 7, 1 + n);
        unsigned short* tm = curm; curm = nxtm; nxtm = tm;
    }
    // after 7 rounds: curm = a1m

    // 6) fused phase3 + obs
    p3obs_k<<<dim3(1, 64, 8), dim3(512), 0, stream>>>(
        curm, G, Smir, BopO, Vn, states, obs);
}

// Round 17
// 621.718 us; speedup vs baseline: 2.6620x; 1.0472x over previous
//
#include <hip/hip_runtime.h>
#include <hip/hip_bf16.h>

// ---------------------------------------------------------------------------
// LinearSystem: chunked parallel scan (128 chunks x 8 steps), bf16 MFMA.
// Round 17 = R16 (651us) with the occupancy lever pushed further: chain
// launches (phase1 x7, KS x7) use 64x64 tiles (32KB LDS, 1024+ blocks ->
// ~4 blocks/CU resident, 4 waves/SIMD vs 2). Drive keeps 128x128; p3obs
// unchanged.
// ---------------------------------------------------------------------------

typedef short bfrag __attribute__((ext_vector_type(8)));   // 8 x bf16 bits
typedef float f32x4 __attribute__((ext_vector_type(4)));

__device__ __host__ inline unsigned short f2bf(float f) {
    union { float f; unsigned u; } x; x.f = f;
    unsigned r = x.u + 0x7fffu + ((x.u >> 16) & 1u);   // RNE
    return (unsigned short)(r >> 16);
}
__device__ inline float bf2f(unsigned short h) {
    union { unsigned u; float f; } x; x.u = ((unsigned)h) << 16;
    return x.f;
}

#define MSL 262144L   // 512*512 matrix stride

struct GemmDesc {
    const unsigned short* a0; const unsigned short* a1;  // A (k < ksplit -> a0)
    const unsigned short* b;                 // B, bf16, (N,K) row-major (B^T)
    float* c;                                // f32 C out (nullable)
    const unsigned short* cmbeta;            // bf16 beta source (beta==2)
    unsigned short* cm;                      // bf16 mirror out (nullable)
    unsigned short* cmT;                     // bf16 transposed mirror (512x512)
    long a0_base, a0_os, a0_is;              // row map: (r>>icl)*os + (r&mask)*is
    long a1_base, a1_os, a1_is;
    long a_zq, a_zr;
    long b_base, b_ldb, b_zq, b_zr;
    long c_base, c_os, c_is, c_zq, c_zr;
    long cm_base, cmb_base, cmT_base;
    long a_shift;                            // prefix rows (copy-only, acc=0)
    int a0_icl, a1_icl, c_icl, zdivl;
    int ksplit, K, beta;                     // beta: 0 none, 2 bf16 cmbeta
    int gxl, gyl, gz_main;
    // aux power-chain slice (bz >= gz_main): 512x512 C = xa[z] @ xb^T
    const unsigned short* xa; const unsigned short* xb;
    unsigned short* xcm; unsigned short* xcmT;
};

// BM x BN tile, BK=64, 4 waves (2x2; wave tile (BM/2) x (BN/2)), 2-phase dbuf.
template<int BM, int BN>
__global__ __launch_bounds__(256) void gemm_k(GemmDesc d) {
    constexpr int MT = BM / 32;              // row frags per wave; also A issues
    constexpr int NT = BN / 32;              // col frags per wave; also B issues
    __shared__ __align__(16) unsigned short As[2][BM * 64];
    __shared__ __align__(16) unsigned short Bs[2][BN * 64];
    const int tid  = threadIdx.x;
    const int lane = tid & 63;
    const int w    = tid >> 6;
    const int wrow = (w >> 1) * (BM / 2), wcol = (w & 1) * (BN / 2);

    // flattened grid + XCD-chunked bijective swizzle (x fastest)
    const unsigned nx = gridDim.x, ny = gridDim.y;
    const unsigned nwg = nx * ny * gridDim.z;
    unsigned wid = blockIdx.x + nx * (blockIdx.y + ny * blockIdx.z);
    if ((nwg & 7) == 0) wid = (wid & 7) * (nwg >> 3) + (wid >> 3);
    const int bx = wid & (nx - 1);
    const int by = (wid >> d.gxl) & (ny - 1);
    int bz = wid >> (d.gxl + d.gyl);

    if (bz >= d.gz_main) {                   // aux: 512x512 power-chain GEMM
        if (by >= (512 / BM)) return;
        const long za = (long)(bz - d.gz_main) * MSL;
        d.a0 = d.xa; d.a0_base = za; d.a0_os = 512; d.a0_is = 0; d.a0_icl = 0;
        d.a1 = nullptr;
        d.b = d.xb; d.b_base = 0; d.b_ldb = 512; d.b_zq = d.b_zr = 0;
        d.K = 512; d.ksplit = 1 << 30; d.beta = 0; d.a_shift = 0;
        d.a_zq = d.a_zr = 0;
        d.c = nullptr; d.cm = d.xcm; d.cm_base = za;
        d.c_os = 512; d.c_is = 0; d.c_icl = 0; d.c_zq = d.c_zr = 0; d.c_base = 0;
        d.cmT = d.xcmT; d.cmT_base = za;
        bz = 0;
    }
    const long zq = (long)bz >> d.zdivl;
    const long zr = (long)bz & ((1L << d.zdivl) - 1);
    const int row0 = by * BM;
    const int col0 = bx * BN;

    const int g_r = tid >> 3;                // staging row within 32-row group
    const int g_k = (tid & 7) * 8;           // 16B k-slot
    const int swz = (g_r & 7) << 3;          // XOR swizzle (8-elem units)
    const long za_ = zq * d.a_zq + zr * d.a_zr;
    const long zb_ = zq * d.b_zq + zr * d.b_zr;

    const long m0a = (1L << d.a0_icl) - 1, m1a = (1L << d.a1_icl) - 1;
    long a0off[MT], a1off[MT], boff[NT];
#pragma unroll
    for (int i = 0; i < MT; ++i) {
        long ar = (long)row0 + i * 32 + g_r - d.a_shift;
        if (ar < 0) ar = 0;
        a0off[i] = d.a0_base + za_ + (ar >> d.a0_icl) * d.a0_os + (ar & m0a) * d.a0_is;
        a1off[i] = d.a1 ? (d.a1_base + za_ + (ar >> d.a1_icl) * d.a1_os + (ar & m1a) * d.a1_is) : 0;
    }
#pragma unroll
    for (int i = 0; i < NT; ++i)
        boff[i] = d.b_base + zb_ + (long)(col0 + i * 32 + g_r) * d.b_ldb;

    bfrag ar_[MT], br_[NT];
    auto LOADT = [&](int t) {
        const int k0 = t * 64;
        const bool s1 = (k0 >= d.ksplit);
        const int kb = (s1 ? k0 - d.ksplit : k0) + g_k;
        const unsigned short* sp = s1 ? d.a1 : d.a0;
#pragma unroll
        for (int i = 0; i < MT; ++i)
            ar_[i] = *(const bfrag*)(sp + (s1 ? a1off[i] : a0off[i]) + kb);
#pragma unroll
        for (int i = 0; i < NT; ++i) br_[i] = *(const bfrag*)(d.b + boff[i] + k0 + g_k);
    };
    auto WRT = [&](int buf) {
#pragma unroll
        for (int i = 0; i < MT; ++i)
            *(bfrag*)&As[buf][(i * 32 + g_r) * 64 + (g_k ^ swz)] = ar_[i];
#pragma unroll
        for (int i = 0; i < NT; ++i)
            *(bfrag*)&Bs[buf][(i * 32 + g_r) * 64 + (g_k ^ swz)] = br_[i];
    };

    f32x4 acc[MT][NT] = {};
    const int nt = d.K / 64;

    LOADT(0); WRT(0); __syncthreads();
    int cur = 0;
    for (int t = 0; t < nt; ++t) {
        if (t + 1 < nt) LOADT(t + 1);        // issue next-tile loads early
#pragma unroll
        for (int ks = 0; ks < 2; ++ks) {
            const int kk = ks * 32 + (lane >> 4) * 8;
            bfrag af[MT], bf_[NT];
#pragma unroll
            for (int mt = 0; mt < MT; ++mt) {
                const int r = wrow + mt * 16 + (lane & 15);
                af[mt] = *(const bfrag*)&As[cur][r * 64 + (kk ^ ((r & 7) << 3))];
            }
#pragma unroll
            for (int nn = 0; nn < NT; ++nn) {
                const int r = wcol + nn * 16 + (lane & 15);
                bf_[nn] = *(const bfrag*)&Bs[cur][r * 64 + (kk ^ ((r & 7) << 3))];
            }
#pragma unroll
            for (int mt = 0; mt < MT; ++mt)
#pragma unroll
                for (int nn = 0; nn < NT; ++nn)
                    acc[mt][nn] = __builtin_amdgcn_mfma_f32_16x16x32_bf16(
                        af[mt], bf_[nn], acc[mt][nn], 0, 0, 0);
        }
        if (t + 1 < nt) WRT(cur ^ 1);        // write-late (hidden under compute)
        __syncthreads();                     // ONE barrier per K-step
        cur ^= 1;
    }

    // ---- epilogue: C/D layout col=lane&15, row=(lane>>4)*4+j ----
    const long zc = zq * d.c_zq + zr * d.c_zr;
    const long mc = (1L << d.c_icl) - 1;
#pragma unroll
    for (int mt = 0; mt < MT; ++mt) {
        const int rb = row0 + wrow + mt * 16 + ((lane >> 4) << 2);
#pragma unroll
        for (int nn = 0; nn < NT; ++nn) {
            const int cc = col0 + wcol + nn * 16 + (lane & 15);
#pragma unroll
            for (int j = 0; j < 4; ++j) {
                const long r = rb + j;
                const long off = zc + (r >> d.c_icl) * d.c_os + (r & mc) * d.c_is + cc;
                float v = (r < d.a_shift) ? 0.0f : acc[mt][nn][j];
                if (d.beta == 2) v += bf2f(d.cmbeta[d.cmb_base + off]);
                if (d.c)  d.c[d.c_base + off] = v;
                if (d.cm) d.cm[d.cm_base + off] = f2bf(v);
                if (d.cmT) d.cmT[d.cmT_base + zc + (long)cc * 512 + r] = f2bf(v);
            }
        }
    }
}

// ---------------------------------------------------------------------------
// Fused phase3 + obs (R8 version, unchanged). Grid (1, 64, 8), 512 thr.
// ---------------------------------------------------------------------------
__global__ __launch_bounds__(512) void p3obs_k(
        const unsigned short* __restrict__ carry, const unsigned short* __restrict__ Gm,
        const unsigned short* __restrict__ Smir, const unsigned short* __restrict__ BopO,
        const float* __restrict__ Vn, float* __restrict__ states, float* __restrict__ obs) {
    __shared__ __align__(16) unsigned char lds[163840];
    unsigned short* As1 = (unsigned short*)(lds);            // [128][64]  (phase A)
    unsigned short* Bs1 = (unsigned short*)(lds + 16384);    // [512][64]  (phase A)
    unsigned short* Sb  = (unsigned short*)(lds);            // [128][512] (phase B)
    unsigned short* A2  = (unsigned short*)(lds);            // [128][64]  (B2, over Sb)
    unsigned short* Ts  = (unsigned short*)(lds + 131072);   // [256][64]  (phase B)

    const int tid  = threadIdx.x;
    const int lane = tid & 63;
    const int w    = tid >> 6;               // 0..7
    const int wm   = w >> 2, wn = w & 3;     // 2 x 4 wave grid
    const int by   = blockIdx.y;             // 0..63
    const int k    = blockIdx.z;             // 0..7
    const unsigned short* G = Gm + (long)k * MSL;   // F^{k+1}

    f32x4 acc[4][8] = {};

    // ---------- GEMM1 ----------
    for (int kt = 0; kt < 8; ++kt) {
        __syncthreads();
#pragma unroll
        for (int i = 0; i < 2; ++i) {        // A tile: carry rows
            const int fi = tid + i * 512;
            const int row = fi >> 3, kk = (fi & 7) * 8;
            const long rg = (long)by * 128 + row;
            const long c = rg >> 6, b = rg & 63;
            bfrag v = *(const bfrag*)(carry + c * 32768 + b * 512 + kt * 64 + kk);
            *(bfrag*)&As1[row * 64 + (kk ^ ((row & 7) << 3))] = v;
        }
#pragma unroll
        for (int i = 0; i < 8; ++i) {        // B tile: G rows (all 512)
            const int fi = tid + i * 512;
            const int row = fi >> 3, kk = (fi & 7) * 8;
            bfrag v = *(const bfrag*)(G + (long)row * 512 + kt * 64 + kk);
            *(bfrag*)&Bs1[row * 64 + (kk ^ ((row & 7) << 3))] = v;
        }
        __syncthreads();
#pragma unroll
        for (int ks = 0; ks < 2; ++ks) {
            const int kk = ks * 32 + (lane >> 4) * 8;
            bfrag af[4], bf_[8];
#pragma unroll
            for (int mt = 0; mt < 4; ++mt) {
                const int r = wm * 64 + mt * 16 + (lane & 15);
                af[mt] = *(const bfrag*)&As1[r * 64 + (kk ^ ((r & 7) << 3))];
            }
#pragma unroll
            for (int nt = 0; nt < 8; ++nt) {
                const int n = wn * 128 + nt * 16 + (lane & 15);
                bf_[nt] = *(const bfrag*)&Bs1[n * 64 + (kk ^ ((n & 7) << 3))];
            }
#pragma unroll
            for (int mt = 0; mt < 4; ++mt)
#pragma unroll
                for (int nt = 0; nt < 8; ++nt)
                    acc[mt][nt] = __builtin_amdgcn_mfma_f32_16x16x32_bf16(
                        af[mt], bf_[nt], acc[mt][nt], 0, 0, 0);
        }
    }
    __syncthreads();                          // As1/Bs1 dead; Sb about to be written

    // ---------- epilogue 1: +local, write states, build Sb ----------
#pragma unroll
    for (int mt = 0; mt < 4; ++mt) {
#pragma unroll
        for (int nt = 0; nt < 8; ++nt) {
#pragma unroll
            for (int j = 0; j < 4; ++j) {
                const int lr = wm * 64 + mt * 16 + ((lane >> 4) << 2) + j;
                const int cc = wn * 128 + nt * 16 + (lane & 15);
                const long rg = (long)by * 128 + lr;
                const long c = rg >> 6, b = rg & 63;
                const long t = c * 8 + k;
                float v = acc[mt][nt][j] + bf2f(Smir[b * 524288L + t * 512 + cc]);
                states[b * 524288L + t * 512 + cc] = v;
                Sb[lr * 512 + (cc ^ ((lr & 7) << 3))] = f2bf(v);
            }
        }
    }

    // ---------- GEMM2: obs = [Sb | cvt(Vn)] @ BopO^T ----------
    f32x4 acc2[4][4] = {};
    for (int kt = 0; kt < 12; ++kt) {
        __syncthreads();
#pragma unroll
        for (int i = 0; i < 4; ++i) {        // Ts: BopO rows 0..255
            const int fi = tid + i * 512;
            const int row = fi >> 3, kk = (fi & 7) * 8;
            bfrag v = *(const bfrag*)(BopO + (long)row * 768 + kt * 64 + kk);
            *(bfrag*)&Ts[row * 64 + (kk ^ ((row & 7) << 3))] = v;
        }
        if (kt >= 8) {
#pragma unroll
            for (int i = 0; i < 2; ++i) {    // A2: Vn f32 -> bf16
                const int fi = tid + i * 512;
                const int row = fi >> 3, kk = (fi & 7) * 8;
                const long rg = (long)by * 128 + row;
                const long c = rg >> 6, b = rg & 63;
                const long t = c * 8 + k;
                const float* p = Vn + b * 262144L + t * 256 + (kt - 8) * 64 + kk;
                f32x4 x0 = *(const f32x4*)p, x1 = *(const f32x4*)(p + 4);
                union { bfrag v; unsigned short h[8]; } u;
#pragma unroll
                for (int q = 0; q < 4; ++q) { u.h[q] = f2bf(x0[q]); u.h[4 + q] = f2bf(x1[q]); }
                *(bfrag*)&A2[row * 64 + (kk ^ ((row & 7) << 3))] = u.v;
            }
        }
        __syncthreads();
#pragma unroll
        for (int ks = 0; ks < 2; ++ks) {
            const int kk = ks * 32 + (lane >> 4) * 8;
            bfrag af[4], bf_[4];
#pragma unroll
            for (int mt = 0; mt < 4; ++mt) {
                const int r = wm * 64 + mt * 16 + (lane & 15);
                af[mt] = (kt < 8)
                    ? *(const bfrag*)&Sb[r * 512 + ((kt * 64 + kk) ^ ((r & 7) << 3))]
                    : *(const bfrag*)&A2[r * 64 + (kk ^ ((r & 7) << 3))];
            }
#pragma unroll
            for (int nt = 0; nt < 4; ++nt) {
                const int n = wn * 64 + nt * 16 + (lane & 15);
                bf_[nt] = *(const bfrag*)&Ts[n * 64 + (kk ^ ((n & 7) << 3))];
            }
#pragma unroll
            for (int mt = 0; mt < 4; ++mt)
#pragma unroll
                for (int nt = 0; nt < 4; ++nt)
                    acc2[mt][nt] = __builtin_amdgcn_mfma_f32_16x16x32_bf16(
                        af[mt], bf_[nt], acc2[mt][nt], 0, 0, 0);
        }
    }
    // ---------- epilogue 2: write obs ----------
#pragma unroll
    for (int mt = 0; mt < 4; ++mt) {
#pragma unroll
        for (int nt = 0; nt < 4; ++nt) {
#pragma unroll
            for (int j = 0; j < 4; ++j) {
                const int lr = wm * 64 + mt * 16 + ((lane >> 4) << 2) + j;
                const int cc = wn * 64 + nt * 16 + (lane & 15);
                const long rg = (long)by * 128 + lr;
                const long c = rg >> 6, b = rg & 63;
                const long t = c * 8 + k;
                obs[b * 262144L + t * 256 + cc] = acc2[mt][nt][j];
            }
        }
    }
}

// f32 -> bf16 bulk conversion, 8 elems/thread.
__global__ void cvt_k(const float* src, unsigned short* dst, long n) {
    long i = ((long)blockIdx.x * 256 + threadIdx.x) * 8;
    const long stride = (long)gridDim.x * 256 * 8;
    for (; i < n; i += stride) {
        f32x4 x0 = *(const f32x4*)(src + i), x1 = *(const f32x4*)(src + i + 4);
        union { bfrag v; unsigned short h[8]; } t;
#pragma unroll
        for (int q = 0; q < 4; ++q) { t.h[q] = f2bf(x0[q]); t.h[4 + q] = f2bf(x1[q]); }
        *(bfrag*)(dst + i) = t.v;
    }
}

// Build bf16 operators: BopD (512x768)=[B_mat|sqrt_S_W], BopO (256x768)=[H|sqrt_S_V],
// G[0]=F, Gt[0]=F^T.
__global__ void build_ops_k(const float* F, const float* Bm, const float* H,
                            const float* sW, const float* sV,
                            unsigned short* bopd, unsigned short* bopo,
                            unsigned short* G1, unsigned short* Gt1) {
    int i = blockIdx.x * 256 + threadIdx.x;
    const int n1 = 512 * 768, n2 = 256 * 768, n3 = 512 * 512;
    if (i < n1) { int n = i / 768, k = i % 768;
        bopd[i] = f2bf(k < 256 ? Bm[n * 256 + k] : sW[n * 512 + (k - 256)]); return; }
    i -= n1;
    if (i < n2) { int o = i / 768, k = i % 768;
        bopo[i] = f2bf(k < 512 ? H[o * 512 + k] : sV[o * 256 + (k - 512)]); return; }
    i -= n2;
    if (i < n3) { G1[i] = f2bf(F[i]); return; }
    i -= n3;
    if (i < n3) { int r = i / 512, c = i % 512; Gt1[i] = f2bf(F[c * 512 + r]); }
}

// Initial carries: dst[c*32768 + b*512 + s]; c==0 from st0 (f32), else from
// Smir local[c-1, 7] = Smir[b*524288 + (c-1)*4096 + 3584 + s].
__global__ void init_carry_k(const float* st0, const unsigned short* Smir,
                             unsigned short* dst) {
    const long i8 = ((long)blockIdx.x * 256 + threadIdx.x) * 8;  // 4,194,304 total
    if (i8 >= 4194304L) return;
    const long c = i8 >> 15, rem = i8 & 32767L;
    const long b = rem >> 9, s = rem & 511L;
    union { bfrag v; unsigned short h[8]; } t;
    if (c == 0) {
        const float* p = st0 + b * 512 + s;
        f32x4 x0 = *(const f32x4*)p, x1 = *(const f32x4*)(p + 4);
#pragma unroll
        for (int q = 0; q < 4; ++q) { t.h[q] = f2bf(x0[q]); t.h[4 + q] = f2bf(x1[q]); }
    } else {
        t.v = *(const bfrag*)(Smir + b * 524288L + (c - 1) * 4096L + 3584L + s);
    }
    *(bfrag*)(dst + i8) = t.v;
}

static GemmDesc D0() {
    GemmDesc d = {};
    d.zdivl = 30;
    d.ksplit = 1 << 30;
    d.b_ldb = 512; d.K = 512;
    d.gz_main = 1 << 30;
    return d;
}

extern "C" void kernel_launch(void* const* d_in, const int* in_sizes, int n_in,
                              void* d_out, int out_size, void* d_ws, size_t ws_size,
                              hipStream_t stream) {
    const float* st0 = (const float*)d_in[0];
    const float* inp = (const float*)d_in[1];
    const float* Wn  = (const float*)d_in[2];
    const float* Vn  = (const float*)d_in[3];
    const float* F   = (const float*)d_in[4];
    const float* Bm  = (const float*)d_in[5];
    const float* H   = (const float*)d_in[6];
    const float* sW  = (const float*)d_in[7];
    const float* sV  = (const float*)d_in[8];

    float* states = (float*)d_out;              // (64,1024,512) f32
    float* obs    = states + 33554432L;         // (64,1024,256) f32

    const long MS = MSL;
    const long CB = 32768;    // 64*512 per-chunk carry block
    const int  NC = 128;      // chunks
    const int  CL = 8;        // chunk length
    const long TOS = 524288;  // batch stride (1024*512)
    const long COS = (long)CL * 512;   // chunk stride = 4096

    // d_out states region: inp/Wn bf16 scratch (dead after drive; p3obs writes
    // states only at the very end).
    unsigned short* inpb = (unsigned short*)states;
    unsigned short* Wnb  = inpb + 16777216L;

    // ws layout (all bf16 bits)
    unsigned short* Smir = (unsigned short*)d_ws;          // 33,554,432
    unsigned short* G    = Smir + 33554432L;               // G[j]=F^{j+1}, j=0..7
    unsigned short* Gt   = G + 8 * MS;
    unsigned short* Qb   = Gt + 8 * MS;                    // F^{16*2^j}, j=0..5
    unsigned short* Qtb  = Qb + 6 * MS;                    // j=0..4 (+1 spare)
    unsigned short* BopD = Qtb + 6 * MS;                   // 512*768
    unsigned short* BopO = BopD + 512 * 768;               // 256*768
    unsigned short* a0m  = BopO + 256 * 768;               // NC*CB carries
    unsigned short* a1m  = a0m + (long)NC * CB;
    (void)in_sizes; (void)n_in; (void)out_size; (void)ws_size;

    auto L128 = [&](const GemmDesc& d, int gx, int gxl, int gy, int gyl, int gz) {
        GemmDesc dd = d; dd.gxl = gxl; dd.gyl = gyl;
        gemm_k<128, 128><<<dim3(gx, gy, gz), dim3(256), 0, stream>>>(dd);
    };
    auto L64 = [&](const GemmDesc& d, int gx, int gxl, int gy, int gyl, int gz) {
        GemmDesc dd = d; dd.gxl = gxl; dd.gyl = gyl;
        gemm_k<64, 64><<<dim3(gx, gy, gz), dim3(256), 0, stream>>>(dd);
    };

    // 0) bf16 prepass: inp, Wn -> d_out scratch
    cvt_k<<<dim3(2048), dim3(256), 0, stream>>>(inp, inpb, 16777216L);
    cvt_k<<<dim3(2048), dim3(256), 0, stream>>>(Wn, Wnb, 33554432L);

    // 1) operators + F, F^T
    build_ops_k<<<dim3(4352), dim3(256), 0, stream>>>(F, Bm, H, sW, sV, BopD, BopO, G, Gt);

    // 2) drive = [inputs | W_noise] @ BopD^T -> Smir (all-bf16), 128x128
    {
        GemmDesc d = D0();
        d.a0 = inpb; d.a0_os = 256;
        d.a1 = Wnb;  d.a1_os = 512;
        d.ksplit = 256; d.K = 768;
        d.b = BopD; d.b_ldb = 768;
        d.cm = Smir; d.c_os = 512;
        L128(d, 4, 2, 512, 9, 1);
    }

    // 3) phase 1 (7 sequential steps, 64x64 tiles: 1024 main blocks = 4/CU)
    //    with fused power-chain aux slices (aux 64 blocks per matrix).
    //    aux k=1: G[1]; k=2: G[2..3]; k=3: G[4..7]; k=4..7: Qb[0..3] (+T)
    for (int k = 1; k < CL; ++k) {
        GemmDesc d = D0();
        d.a0 = Smir; d.a0_base = (long)(k - 1) * 512;
        d.a0_icl = 7; d.a0_is = COS; d.a0_os = TOS;
        d.b = G;  // F
        d.c_base = (long)k * 512;
        d.c_icl = 7; d.c_is = COS; d.c_os = TOS;
        d.beta = 2; d.cmbeta = Smir; d.cmb_base = (long)k * 512;
        d.cm = Smir; d.cm_base = (long)k * 512;
        d.gz_main = 1;
        int n;
        if (k == 1)      { d.xa = G;           d.xb = Gt;           d.xcm = G + MS;      d.xcmT = Gt + MS;      n = 1; }
        else if (k == 2) { d.xa = G;           d.xb = Gt + MS;      d.xcm = G + 2 * MS;  d.xcmT = Gt + 2 * MS;  n = 2; }
        else if (k == 3) { d.xa = G;           d.xb = Gt + 3 * MS;  d.xcm = G + 4 * MS;  d.xcmT = Gt + 4 * MS;  n = 4; }
        else if (k == 4) { d.xa = G + 7 * MS;  d.xb = Gt + 7 * MS;  d.xcm = Qb;          d.xcmT = Qtb;          n = 1; }
        else             { int j = k - 5;
                           d.xa = Qb + j * MS; d.xb = Qtb + j * MS; d.xcm = Qb + (j+1)*MS; d.xcmT = Qtb + (j+1)*MS; n = 1; }
        L64(d, 8, 3, 128, 7, 1 + n);
    }

    // 4) initial carries a[c]
    init_carry_k<<<dim3(2048), dim3(256), 0, stream>>>(st0, Smir, a0m);

    // 5) Kogge-Stone (bf16 carries, 64x64): nxt[r] = cur[r] +
    //    (r>=s*64 ? cur[r-s*64]@(F^{8s})^T : 0)
    //    aux s=1: Qb[4]=F^256 (+T); s=2: Qb[5]=F^512
    unsigned short* curm = a0m;
    unsigned short* nxtm = a1m;
    for (int s = 1; s < NC; s <<= 1) {
        GemmDesc d = D0();
        d.a0 = curm; d.a0_os = 512;
        d.a_shift = (long)s * 64;
        if (s == 1) { d.b = G + 7 * MS; }
        else        { d.b = Qb + (long)(__builtin_ctz(s) - 1) * MS; }
        d.beta = 2; d.cmbeta = curm; d.cmb_base = 0;
        d.cm = nxtm; d.c_os = 512;
        int n = 0;
        if (s == 1) { d.gz_main = 1; d.xa = Qb + 3 * MS; d.xb = Qtb + 3 * MS;
                      d.xcm = Qb + 4 * MS; d.xcmT = Qtb + 4 * MS; n = 1; }
        if (s == 2) { d.gz_main = 1; d.xa = Qb + 4 * MS; d.xb = Qtb + 4 * MS;
                      d.xcm = Qb + 5 * MS; d.xcmT = nullptr; n = 1; }
        L64(d, 8, 3, 128, 7, 1 + n);
        unsigned short* tm = curm; curm = nxtm; nxtm = tm;
    }
    // after 7 rounds: curm = a1m

    // 6) fused phase3 + obs
    p3obs_k<<<dim3(1, 64, 8), dim3(512), 0, stream>>>(
        curm, G, Smir, BopO, Vn, states, obs);
}